// Round 2
// baseline (1480.270 us; speedup 1.0000x reference)
//
#include <hip/hip_runtime.h>
#include <hip/hip_bf16.h>

#define NN 50000
#define NE 500000
#define DH 128

// ------------------------- CSR build kernels -------------------------

__global__ void k_count(const int* __restrict__ dst, int* __restrict__ cnt, int E) {
    int e = blockIdx.x * 256 + threadIdx.x;
    if (e < E) atomicAdd(&cnt[dst[e]], 1);
}

__global__ void k_scan1(const int* __restrict__ cnt, int* __restrict__ bsum, int n) {
    int t = threadIdx.x;
    int idx = blockIdx.x * 256 + t;
    int v = (idx < n) ? cnt[idx] : 0;
#pragma unroll
    for (int m = 1; m < 64; m <<= 1) v += __shfl_xor(v, m);
    __shared__ int w4[4];
    if ((t & 63) == 0) w4[t >> 6] = v;
    __syncthreads();
    if (t == 0) bsum[blockIdx.x] = w4[0] + w4[1] + w4[2] + w4[3];
}

__global__ void k_scan2(int* __restrict__ bsum, int nb, int* __restrict__ rs, int n, int E) {
    __shared__ int s[256];
    int t = threadIdx.x;
    s[t] = (t < nb) ? bsum[t] : 0;
    __syncthreads();
#pragma unroll
    for (int off = 1; off < 256; off <<= 1) {
        int v = (t >= off) ? s[t - off] : 0;
        __syncthreads();
        s[t] += v;
        __syncthreads();
    }
    if (t < nb) bsum[t] = (t == 0) ? 0 : s[t - 1];
    if (t == 0) rs[n] = E;
}

__global__ void k_scan3(const int* __restrict__ cnt, const int* __restrict__ bsum,
                        int* __restrict__ rs, int n) {
    __shared__ int s[256];
    int t = threadIdx.x;
    int idx = blockIdx.x * 256 + t;
    int mine = (idx < n) ? cnt[idx] : 0;
    s[t] = mine;
    __syncthreads();
#pragma unroll
    for (int off = 1; off < 256; off <<= 1) {
        int v = (t >= off) ? s[t - off] : 0;
        __syncthreads();
        s[t] += v;
        __syncthreads();
    }
    if (idx < n) rs[idx] = bsum[blockIdx.x] + s[t] - mine;
}

__global__ void k_scatter(const int* __restrict__ src, const int* __restrict__ dst,
                          const float* __restrict__ val, int* __restrict__ cur,
                          int* __restrict__ srcs, float* __restrict__ vals, int E) {
    int e = blockIdx.x * 256 + threadIdx.x;
    if (e >= E) return;
    int d = dst[e];
    int pos = atomicAdd(&cur[d], 1);
    srcs[pos] = src[e];
    vals[pos] = val[e];
}

// ------------------------- GEMM -------------------------
// MODE 0: Out = X@W + Bias        (M,BN)
// MODE 1: Out = relu(X@W + Bias)
// MODE 2: atomicAdd(Out, sum_rows( tanh(X@W + Bias) @ Q ))   (Out is 1 float)
template <int BN, int CPT, int MODE>
__global__ __launch_bounds__(256) void k_gemm(const float* __restrict__ X, int M, int K,
                                              const float* __restrict__ W,
                                              const float* __restrict__ Bias,
                                              const float* __restrict__ Q,
                                              float* __restrict__ Out) {
    constexpr int BK = 32;
    constexpr int BM = 64;
    constexpr int LDX = BM + 4;  // 68: multiple of 4 for aligned float4 LDS reads
    __shared__ float xs[BK][LDX];
    __shared__ float ws[BK][BN];
    int t = threadIdx.x;
    int tx = t & 31, ty = t >> 5;
    int gm0 = blockIdx.x * BM;
    int c0 = tx * CPT;

    float acc[8][CPT];
#pragma unroll
    for (int i = 0; i < 8; ++i)
#pragma unroll
        for (int j = 0; j < CPT; ++j) acc[i][j] = 0.f;

    for (int k0 = 0; k0 < K; k0 += BK) {
        // stage X (64 rows x 32 k), transposed into xs[k][m]
#pragma unroll
        for (int i = 0; i < 2; ++i) {
            int idx4 = t + i * 256;  // 0..511 float4s
            int m = idx4 >> 3;       // 0..63
            int kq = idx4 & 7;       // 0..7
            int gm = gm0 + m;
            float4 v = make_float4(0.f, 0.f, 0.f, 0.f);
            if (gm < M) v = *(const float4*)&X[(size_t)gm * K + k0 + kq * 4];
            xs[kq * 4 + 0][m] = v.x;
            xs[kq * 4 + 1][m] = v.y;
            xs[kq * 4 + 2][m] = v.z;
            xs[kq * 4 + 3][m] = v.w;
        }
        // stage W (32 k x BN)
        constexpr int WLOAD = (BK * BN) / (256 * 4);
#pragma unroll
        for (int i = 0; i < WLOAD; ++i) {
            int idx4 = t + i * 256;
            int k = idx4 / (BN / 4);
            int n4 = idx4 % (BN / 4);
            *(float4*)&ws[k][n4 * 4] = *(const float4*)&W[(size_t)(k0 + k) * BN + n4 * 4];
        }
        __syncthreads();
#pragma unroll
        for (int k = 0; k < BK; ++k) {
            float wv[CPT];
            if (CPT == 4) {
                float4 w4 = *(const float4*)&ws[k][c0];
                wv[0] = w4.x; wv[1] = w4.y; wv[2] = w4.z; wv[3] = w4.w;
            } else {
                float2 w2 = *(const float2*)&ws[k][c0];
                wv[0] = w2.x; wv[1] = w2.y;
            }
            float4 xv0 = *(const float4*)&xs[k][ty * 8];
            float4 xv1 = *(const float4*)&xs[k][ty * 8 + 4];
            float xv[8] = {xv0.x, xv0.y, xv0.z, xv0.w, xv1.x, xv1.y, xv1.z, xv1.w};
#pragma unroll
            for (int i = 0; i < 8; ++i)
#pragma unroll
                for (int j = 0; j < CPT; ++j) acc[i][j] += xv[i] * wv[j];
        }
        __syncthreads();
    }

    float bv[CPT];
#pragma unroll
    for (int j = 0; j < CPT; ++j) bv[j] = Bias[c0 + j];

    if (MODE == 2) {
        float qv[CPT];
#pragma unroll
        for (int j = 0; j < CPT; ++j) qv[j] = Q[c0 + j];
        float tot = 0.f;
#pragma unroll
        for (int i = 0; i < 8; ++i) {
            int gm = gm0 + ty * 8 + i;
            if (gm < M) {
#pragma unroll
                for (int j = 0; j < CPT; ++j) tot += tanhf(acc[i][j] + bv[j]) * qv[j];
            }
        }
#pragma unroll
        for (int m = 1; m < 64; m <<= 1) tot += __shfl_xor(tot, m);
        __shared__ float blksum;
        if (t == 0) blksum = 0.f;
        __syncthreads();
        if ((t & 63) == 0) atomicAdd(&blksum, tot);
        __syncthreads();
        if (t == 0) atomicAdd(Out, blksum);
    } else {
#pragma unroll
        for (int i = 0; i < 8; ++i) {
            int gm = gm0 + ty * 8 + i;
            if (gm >= M) continue;
            float o[CPT];
#pragma unroll
            for (int j = 0; j < CPT; ++j) {
                float v = acc[i][j] + bv[j];
                if (MODE == 1) v = fmaxf(v, 0.f);
                o[j] = v;
            }
            if (CPT == 4)
                *(float4*)&Out[(size_t)gm * BN + c0] = make_float4(o[0], o[1], o[2], o[3]);
            else
                *(float2*)&Out[(size_t)gm * BN + c0] = make_float2(o[0], o[1]);
        }
    }
}

// ------------------------- SpMM (fused + a2*xdst) -------------------------
// out[i][:] = a2[i]*Xd[i][:] + sum_{e in row i} vals[e]*Xs[srcs[e]][:]
__global__ void k_spmm(const int* __restrict__ rs, const int* __restrict__ srcs,
                       const float* __restrict__ vals, const float* __restrict__ Xs,
                       const float* __restrict__ Xd, const float* __restrict__ a2,
                       float* __restrict__ Out, int n) {
    int row = blockIdx.x * 4 + (threadIdx.x >> 6);
    if (row >= n) return;
    int lane = threadIdx.x & 63;
    int e0 = rs[row], e1 = rs[row + 1];
    float a = a2[row];
    float2 xd = *(const float2*)&Xd[(size_t)row * DH + lane * 2];
    float accx = a * xd.x, accy = a * xd.y;
    for (int e = e0; e < e1; ++e) {
        int s = srcs[e];
        float v = vals[e];
        float2 xv = *(const float2*)&Xs[(size_t)s * DH + lane * 2];
        accx += v * xv.x;
        accy += v * xv.y;
    }
    *(float2*)&Out[(size_t)row * DH + lane * 2] = make_float2(accx, accy);
}

// ------------------------- beta + combine -------------------------
__global__ void k_beta(const float* __restrict__ ssum, float* __restrict__ beta, float invN) {
    float s0 = ssum[0] * invN, s1 = ssum[1] * invN;
    float m = fmaxf(s0, s1);
    float e0 = expf(s0 - m), e1 = expf(s1 - m);
    float d = e0 + e1;
    beta[0] = e0 / d;
    beta[1] = e1 / d;
}

__global__ void k_combine(const float* __restrict__ h1, const float* __restrict__ h2,
                          const float* __restrict__ beta, float* __restrict__ out, int n4) {
    int i = blockIdx.x * 256 + threadIdx.x;
    if (i >= n4) return;
    float b0 = beta[0], b1 = beta[1];
    float4 a = ((const float4*)h1)[i];
    float4 b = ((const float4*)h2)[i];
    float4 o;
    o.x = fmaxf(b0 * a.x + b1 * b.x, 0.f);
    o.y = fmaxf(b0 * a.y + b1 * b.y, 0.f);
    o.z = fmaxf(b0 * a.z + b1 * b.z, 0.f);
    o.w = fmaxf(b0 * a.w + b1 * b.w, 0.f);
    ((float4*)out)[i] = o;
}

// ------------------------- launch -------------------------

extern "C" void kernel_launch(void* const* d_in, const int* in_sizes, int n_in, void* d_out,
                              int out_size, void* d_ws, size_t ws_size, hipStream_t stream) {
    (void)in_sizes; (void)n_in; (void)out_size; (void)ws_size;

    const float* x_A = (const float*)d_in[0];
    const float* x_B = (const float*)d_in[1];
    const int* srcI[4];
    const int* dstI[4];
    const float* valI[4];
    const float* a2I[4];
    for (int r = 0; r < 4; ++r) {  // AA, AB, BB, BA
        srcI[r] = (const int*)d_in[2 + r * 4];
        dstI[r] = (const int*)d_in[3 + r * 4];
        valI[r] = (const float*)d_in[4 + r * 4];
        a2I[r] = (const float*)d_in[5 + r * 4];
    }
    const float* fc1A_w = (const float*)d_in[18];
    const float* fc1A_b = (const float*)d_in[19];
    const float* fc1B_w = (const float*)d_in[20];
    const float* fc1B_b = (const float*)d_in[21];
    const float* fcs_w[2] = {(const float*)d_in[22], (const float*)d_in[30]};
    const float* fcs_b[2] = {(const float*)d_in[23], (const float*)d_in[31]};
    const float* saA_w[2] = {(const float*)d_in[24], (const float*)d_in[32]};
    const float* saA_b[2] = {(const float*)d_in[25], (const float*)d_in[33]};
    const float* saA_q[2] = {(const float*)d_in[26], (const float*)d_in[34]};
    const float* saB_w[2] = {(const float*)d_in[27], (const float*)d_in[35]};
    const float* saB_b[2] = {(const float*)d_in[28], (const float*)d_in[36]};
    const float* saB_q[2] = {(const float*)d_in[29], (const float*)d_in[37]};
    const float* fc2_w = (const float*)d_in[38];
    const float* fc2_b = (const float*)d_in[39];

    // workspace carve
    char* p = (char*)d_ws;
    auto take = [&](size_t bytes) -> void* {
        void* r = (void*)p;
        p += (bytes + 255) & ~(size_t)255;
        return r;
    };
    const size_t NF = (size_t)NN * DH;
    float* xA0 = (float*)take(NF * 4);
    float* xA1 = (float*)take(NF * 4);
    float* xB0 = (float*)take(NF * 4);
    float* xB1 = (float*)take(NF * 4);
    float* h1 = (float*)take(NF * 4);
    float* h2 = (float*)take(NF * 4);
    int* rs[4];
    int* srcS[4];
    float* valS[4];
    for (int r = 0; r < 4; ++r) {
        rs[r] = (int*)take((NN + 1) * 4);
        srcS[r] = (int*)take((size_t)NE * 4);
        valS[r] = (float*)take((size_t)NE * 4);
    }
    int* cnt = (int*)take(NN * 4);
    int* cur = (int*)take(NN * 4);
    int* bsum = (int*)take(256 * 4);
    float* ssum = (float*)take(16 * 4);
    float* beta = (float*)take(16 * 4);

    const int GE = (NE + 255) / 256;          // edge-parallel grid
    const int GS = (NN + 255) / 256;          // 196 scan blocks
    const int GG = (NN + 63) / 64;            // 782 gemm blocks
    const int GP = (NN + 3) / 4;              // 12500 spmm blocks
    const int GC = (int)(NF / 4 / 256);       // 6250 combine blocks
    const float invN = 1.0f / (float)NN;

    // ---- CSR build (4 relations) ----
    for (int r = 0; r < 4; ++r) {
        hipMemsetAsync(cnt, 0, NN * 4, stream);
        k_count<<<GE, 256, 0, stream>>>(dstI[r], cnt, NE);
        k_scan1<<<GS, 256, 0, stream>>>(cnt, bsum, NN);
        k_scan2<<<1, 256, 0, stream>>>(bsum, GS, rs[r], NN, NE);
        k_scan3<<<GS, 256, 0, stream>>>(cnt, bsum, rs[r], NN);
        hipMemcpyAsync(cur, rs[r], NN * 4, hipMemcpyDeviceToDevice, stream);
        k_scatter<<<GE, 256, 0, stream>>>(srcI[r], dstI[r], valI[r], cur, srcS[r], valS[r], NE);
    }
    hipMemsetAsync(ssum, 0, 16 * 4, stream);

    // ---- fc1 + relu ----
    k_gemm<128, 4, 1><<<GG, 256, 0, stream>>>(x_A, NN, 256, fc1A_w, fc1A_b, nullptr, xA0);
    k_gemm<128, 4, 1><<<GG, 256, 0, stream>>>(x_B, NN, 128, fc1B_w, fc1B_b, nullptr, xB0);

    for (int h = 0; h < 2; ++h) {
        // shared per-hop linear
        k_gemm<128, 4, 0><<<GG, 256, 0, stream>>>(xA0, NN, 128, fcs_w[h], fcs_b[h], nullptr, xA1);
        k_gemm<128, 4, 0><<<GG, 256, 0, stream>>>(xB0, NN, 128, fcs_w[h], fcs_b[h], nullptr, xB1);
        // type A: relations AA (r=0), AB (r=1)
        k_spmm<<<GP, 256, 0, stream>>>(rs[0], srcS[0], valS[0], xA1, xA1, a2I[0], h1, NN);
        k_spmm<<<GP, 256, 0, stream>>>(rs[1], srcS[1], valS[1], xB1, xA1, a2I[1], h2, NN);
        k_gemm<128, 4, 2><<<GG, 256, 0, stream>>>(h1, NN, 128, saA_w[h], saA_b[h], saA_q[h],
                                                  ssum + h * 4 + 0);
        k_gemm<128, 4, 2><<<GG, 256, 0, stream>>>(h2, NN, 128, saA_w[h], saA_b[h], saA_q[h],
                                                  ssum + h * 4 + 1);
        k_beta<<<1, 1, 0, stream>>>(ssum + h * 4 + 0, beta + h * 4 + 0, invN);
        k_combine<<<GC, 256, 0, stream>>>(h1, h2, beta + h * 4 + 0, xA0, (int)(NF / 4));
        // type B: relations BB (r=2), BA (r=3); BA gathers the UPDATED xA
        k_spmm<<<GP, 256, 0, stream>>>(rs[2], srcS[2], valS[2], xB1, xB1, a2I[2], h1, NN);
        k_spmm<<<GP, 256, 0, stream>>>(rs[3], srcS[3], valS[3], xA0, xB1, a2I[3], h2, NN);
        k_gemm<128, 4, 2><<<GG, 256, 0, stream>>>(h1, NN, 128, saB_w[h], saB_b[h], saB_q[h],
                                                  ssum + h * 4 + 2);
        k_gemm<128, 4, 2><<<GG, 256, 0, stream>>>(h2, NN, 128, saB_w[h], saB_b[h], saB_q[h],
                                                  ssum + h * 4 + 3);
        k_beta<<<1, 1, 0, stream>>>(ssum + h * 4 + 2, beta + h * 4 + 2, invN);
        k_combine<<<GC, 256, 0, stream>>>(h1, h2, beta + h * 4 + 2, xB0, (int)(NF / 4));
    }

    // ---- fc2 (no relu), f32 out ----
    k_gemm<64, 2, 0><<<GG, 256, 0, stream>>>(xA0, NN, 128, fc2_w, fc2_b, nullptr, (float*)d_out);
}

// Round 3
// 1407.366 us; speedup vs baseline: 1.0518x; 1.0518x over previous
//
#include <hip/hip_runtime.h>
#include <hip/hip_bf16.h>

#define NN 50000
#define NE 500000
#define DH 128

using short8 = __attribute__((ext_vector_type(8))) short;
using f32x4 = __attribute__((ext_vector_type(4))) float;

__device__ __forceinline__ float b2f(unsigned short u) {
    unsigned v = (unsigned)u << 16;
    return __builtin_bit_cast(float, v);
}
__device__ __forceinline__ unsigned short f2b(float f) {
    return __builtin_bit_cast(unsigned short, __float2bfloat16(f));
}

// ------------------------- CSR build kernels -------------------------

__global__ void k_count(const int* __restrict__ dst, int* __restrict__ cnt, int E) {
    int e = blockIdx.x * 256 + threadIdx.x;
    if (e < E) atomicAdd(&cnt[dst[e]], 1);
}

__global__ void k_scan1(const int* __restrict__ cnt, int* __restrict__ bsum, int n) {
    int t = threadIdx.x;
    int idx = blockIdx.x * 256 + t;
    int v = (idx < n) ? cnt[idx] : 0;
#pragma unroll
    for (int m = 1; m < 64; m <<= 1) v += __shfl_xor(v, m);
    __shared__ int w4[4];
    if ((t & 63) == 0) w4[t >> 6] = v;
    __syncthreads();
    if (t == 0) bsum[blockIdx.x] = w4[0] + w4[1] + w4[2] + w4[3];
}

__global__ void k_scan2(int* __restrict__ bsum, int nb, int* __restrict__ rs, int n, int E) {
    __shared__ int s[256];
    int t = threadIdx.x;
    s[t] = (t < nb) ? bsum[t] : 0;
    __syncthreads();
#pragma unroll
    for (int off = 1; off < 256; off <<= 1) {
        int v = (t >= off) ? s[t - off] : 0;
        __syncthreads();
        s[t] += v;
        __syncthreads();
    }
    if (t < nb) bsum[t] = (t == 0) ? 0 : s[t - 1];
    if (t == 0) rs[n] = E;
}

__global__ void k_scan3(const int* __restrict__ cnt, const int* __restrict__ bsum,
                        int* __restrict__ rs, int n) {
    __shared__ int s[256];
    int t = threadIdx.x;
    int idx = blockIdx.x * 256 + t;
    int mine = (idx < n) ? cnt[idx] : 0;
    s[t] = mine;
    __syncthreads();
#pragma unroll
    for (int off = 1; off < 256; off <<= 1) {
        int v = (t >= off) ? s[t - off] : 0;
        __syncthreads();
        s[t] += v;
        __syncthreads();
    }
    if (idx < n) rs[idx] = bsum[blockIdx.x] + s[t] - mine;
}

__global__ void k_scatter(const int* __restrict__ src, const int* __restrict__ dst,
                          const float* __restrict__ val, int* __restrict__ cur,
                          int* __restrict__ srcs, float* __restrict__ vals, int E) {
    int e = blockIdx.x * 256 + threadIdx.x;
    if (e >= E) return;
    int d = dst[e];
    int pos = atomicAdd(&cur[d], 1);
    srcs[pos] = src[e];
    vals[pos] = val[e];
}

// ------------------------- fp32 -> bf16 bulk convert -------------------------

__global__ void k_f2b(const float* __restrict__ src, unsigned short* __restrict__ dst, int n4) {
    int i = blockIdx.x * 256 + threadIdx.x;
    if (i >= n4) return;
    float4 v = ((const float4*)src)[i];
    unsigned short o0 = f2b(v.x), o1 = f2b(v.y), o2 = f2b(v.z), o3 = f2b(v.w);
    unsigned lo = (unsigned)o0 | ((unsigned)o1 << 16);
    unsigned hi = (unsigned)o2 | ((unsigned)o3 << 16);
    ((uint2*)dst)[i] = make_uint2(lo, hi);
}

// ------------------------- weight transpose + swizzle pack -------------------------
// dst layout: bf16 at byte ((n*K + k)*2) ^ ((n&7)<<4)  -- matches GEMM's swizzled ds_read

struct WDesc { const float* src; unsigned short* dst; int K; int N; int start; };
struct WPack { WDesc d[9]; };

__global__ void k_wt(WPack p) {
    int gid = blockIdx.x * 256 + threadIdx.x;
#pragma unroll
    for (int i = 0; i < 9; ++i) {
        int K = p.d[i].K, N = p.d[i].N;
        int local = gid - p.d[i].start;
        if (local >= 0 && local < K * N) {
            int k = local / N;
            int n = local - k * N;
            float w = p.d[i].src[local];
            unsigned byte = ((unsigned)(n * K + k) * 2u) ^ ((unsigned)(n & 7) << 4);
            *(unsigned short*)((char*)p.d[i].dst + byte) = f2b(w);
            return;
        }
    }
}

// ------------------------- MFMA GEMM -------------------------
// C(M x N) = X(M x K, bf16) @ W(K x N)  via pre-transposed+swizzled WT
// MODE 0: Out = X@W + Bias
// MODE 1: Out = relu(X@W + Bias)
// MODE 2: atomicAdd(Sout, sum_rows( tanh(X@W + Bias) @ Q ))
template <int KT, int NF, int MODE, bool OUTF32>
__global__ __launch_bounds__(256) void k_mm(const unsigned short* __restrict__ X, int M,
                                            const unsigned short* __restrict__ WT,
                                            const float* __restrict__ Bias,
                                            const float* __restrict__ Q,
                                            void* __restrict__ OutV,
                                            float* __restrict__ Sout) {
    constexpr int K = KT * 32;
    constexpr int N = NF * 16;
    __shared__ unsigned short wlds[K * N];
    int t = threadIdx.x;

    // linear stage of pre-swizzled weights (16B per thread per iter)
    constexpr int CH = K * N * 2 / 16;
    const uint4* wg = (const uint4*)WT;
    uint4* wl = (uint4*)wlds;
#pragma unroll
    for (int i = 0; i < CH / 256; ++i) wl[t + i * 256] = wg[t + i * 256];

    int l = t & 63, w = t >> 6;
    int m0 = blockIdx.x * 64 + w * 16;
    int arow = m0 + (l & 15);
    if (arow >= M) arow = M - 1;  // clamp; OOB rows masked in epilogue
    int kh = (l >> 4) * 8;

    // A fragments straight from global (bf16 activations), 16B/lane
    short8 a[KT];
    const unsigned short* xp = X + (size_t)arow * K + kh;
#pragma unroll
    for (int kt = 0; kt < KT; ++kt) a[kt] = *(const short8*)(xp + kt * 32);

    __syncthreads();

    f32x4 acc[NF];
#pragma unroll
    for (int i = 0; i < NF; ++i) acc[i] = (f32x4){0.f, 0.f, 0.f, 0.f};

    unsigned sw = (unsigned)((l & 7) << 4);  // (n&7)<<4, n&7 == col0&7
#pragma unroll
    for (int nf = 0; nf < NF; ++nf) {
        unsigned base = (unsigned)((nf * 16 + (l & 15)) * K) * 2u;
#pragma unroll
        for (int kt = 0; kt < KT; ++kt) {
            unsigned byte = (base + (unsigned)(kt * 32 + kh) * 2u) ^ sw;
            short8 b = *(const short8*)((const char*)wlds + byte);
            acc[nf] = __builtin_amdgcn_mfma_f32_16x16x32_bf16(a[kt], b, acc[nf], 0, 0, 0);
        }
    }

    // epilogue: C/D layout col=lane&15, row=(lane>>4)*4+r  [m89-verified]
    int col0 = l & 15;
    int rbase = m0 + (l >> 4) * 4;
    if (MODE == 2) {
        float tot = 0.f;
#pragma unroll
        for (int nf = 0; nf < NF; ++nf) {
            int c = nf * 16 + col0;
            float bv = Bias[c], qv = Q[c];
#pragma unroll
            for (int r = 0; r < 4; ++r)
                if (rbase + r < M) tot += tanhf(acc[nf][r] + bv) * qv;
        }
#pragma unroll
        for (int m = 1; m < 64; m <<= 1) tot += __shfl_xor(tot, m);
        if (l == 0) atomicAdd(Sout, tot);
    } else {
#pragma unroll
        for (int nf = 0; nf < NF; ++nf) {
            int c = nf * 16 + col0;
            float bv = Bias[c];
#pragma unroll
            for (int r = 0; r < 4; ++r) {
                int row = rbase + r;
                if (row >= M) continue;
                float v = acc[nf][r] + bv;
                if (MODE == 1) v = fmaxf(v, 0.f);
                if (OUTF32)
                    ((float*)OutV)[(size_t)row * N + c] = v;
                else
                    ((unsigned short*)OutV)[(size_t)row * N + c] = f2b(v);
            }
        }
    }
}

// ------------------------- SpMM (bf16 gather, fp32 accum) -------------------------
// out[i][:] = a2[i]*Xd[i][:] + sum_{e in row i} vals[e]*Xs[srcs[e]][:]
__global__ void k_spmm(const int* __restrict__ rs, const int* __restrict__ srcs,
                       const float* __restrict__ vals, const unsigned short* __restrict__ Xs,
                       const unsigned short* __restrict__ Xd, const float* __restrict__ a2,
                       unsigned short* __restrict__ Out, int n) {
    int row = blockIdx.x * 4 + (threadIdx.x >> 6);
    if (row >= n) return;
    int lane = threadIdx.x & 63;
    int e0 = rs[row], e1 = rs[row + 1];
    float a = a2[row];
    unsigned xd = *(const unsigned*)&Xd[(size_t)row * DH + lane * 2];
    float accx = a * b2f((unsigned short)xd);
    float accy = a * b2f((unsigned short)(xd >> 16));
    for (int e = e0; e < e1; ++e) {
        int s = srcs[e];
        float v = vals[e];
        unsigned xv = *(const unsigned*)&Xs[(size_t)s * DH + lane * 2];
        accx += v * b2f((unsigned short)xv);
        accy += v * b2f((unsigned short)(xv >> 16));
    }
    unsigned o = (unsigned)f2b(accx) | ((unsigned)f2b(accy) << 16);
    *(unsigned*)&Out[(size_t)row * DH + lane * 2] = o;
}

// ------------------------- beta + combine -------------------------
__global__ void k_beta(const float* __restrict__ ssum, float* __restrict__ beta, float invN) {
    float s0 = ssum[0] * invN, s1 = ssum[1] * invN;
    float m = fmaxf(s0, s1);
    float e0 = expf(s0 - m), e1 = expf(s1 - m);
    float d = e0 + e1;
    beta[0] = e0 / d;
    beta[1] = e1 / d;
}

__global__ void k_combine(const unsigned short* __restrict__ h1,
                          const unsigned short* __restrict__ h2,
                          const float* __restrict__ beta, unsigned short* __restrict__ out,
                          int n8) {
    int i = blockIdx.x * 256 + threadIdx.x;
    if (i >= n8) return;
    float b0 = beta[0], b1 = beta[1];
    short8 A = ((const short8*)h1)[i];
    short8 B = ((const short8*)h2)[i];
    short8 O;
#pragma unroll
    for (int j = 0; j < 8; ++j) {
        float v = b0 * b2f((unsigned short)A[j]) + b1 * b2f((unsigned short)B[j]);
        O[j] = (short)f2b(fmaxf(v, 0.f));
    }
    ((short8*)out)[i] = O;
}

// ------------------------- launch -------------------------

extern "C" void kernel_launch(void* const* d_in, const int* in_sizes, int n_in, void* d_out,
                              int out_size, void* d_ws, size_t ws_size, hipStream_t stream) {
    (void)in_sizes; (void)n_in; (void)out_size; (void)ws_size;

    const float* x_A = (const float*)d_in[0];
    const float* x_B = (const float*)d_in[1];
    const int* srcI[4];
    const int* dstI[4];
    const float* valI[4];
    const float* a2I[4];
    for (int r = 0; r < 4; ++r) {  // AA, AB, BB, BA
        srcI[r] = (const int*)d_in[2 + r * 4];
        dstI[r] = (const int*)d_in[3 + r * 4];
        valI[r] = (const float*)d_in[4 + r * 4];
        a2I[r] = (const float*)d_in[5 + r * 4];
    }
    const float* fc1A_w = (const float*)d_in[18];
    const float* fc1A_b = (const float*)d_in[19];
    const float* fc1B_w = (const float*)d_in[20];
    const float* fc1B_b = (const float*)d_in[21];
    const float* fcs_w[2] = {(const float*)d_in[22], (const float*)d_in[30]};
    const float* fcs_b[2] = {(const float*)d_in[23], (const float*)d_in[31]};
    const float* saA_w[2] = {(const float*)d_in[24], (const float*)d_in[32]};
    const float* saA_b[2] = {(const float*)d_in[25], (const float*)d_in[33]};
    const float* saA_q[2] = {(const float*)d_in[26], (const float*)d_in[34]};
    const float* saB_w[2] = {(const float*)d_in[27], (const float*)d_in[35]};
    const float* saB_b[2] = {(const float*)d_in[28], (const float*)d_in[36]};
    const float* saB_q[2] = {(const float*)d_in[29], (const float*)d_in[37]};
    const float* fc2_w = (const float*)d_in[38];
    const float* fc2_b = (const float*)d_in[39];

    // workspace carve
    char* p = (char*)d_ws;
    auto take = [&](size_t bytes) -> void* {
        void* r = (void*)p;
        p += (bytes + 255) & ~(size_t)255;
        return r;
    };
    const size_t NF = (size_t)NN * DH;
    typedef unsigned short u16;
    u16* xAbf = (u16*)take((size_t)NN * 256 * 2);  // bf16 x_A
    u16* xBbf = (u16*)take((size_t)NN * 128 * 2);  // bf16 x_B
    u16* xA0 = (u16*)take(NF * 2);
    u16* xA1 = (u16*)take(NF * 2);
    u16* xB0 = (u16*)take(NF * 2);
    u16* xB1 = (u16*)take(NF * 2);
    u16* h1 = (u16*)take(NF * 2);
    u16* h2 = (u16*)take(NF * 2);
    u16* wt_fc1A = (u16*)take(256 * 128 * 2);
    u16* wt_fc1B = (u16*)take(128 * 128 * 2);
    u16* wt_fcs[2] = {(u16*)take(128 * 128 * 2), (u16*)take(128 * 128 * 2)};
    u16* wt_saA[2] = {(u16*)take(128 * 128 * 2), (u16*)take(128 * 128 * 2)};
    u16* wt_saB[2] = {(u16*)take(128 * 128 * 2), (u16*)take(128 * 128 * 2)};
    u16* wt_fc2 = (u16*)take(128 * 64 * 2);
    int* rs[4];
    int* srcS[4];
    float* valS[4];
    for (int r = 0; r < 4; ++r) {
        rs[r] = (int*)take((NN + 1) * 4);
        srcS[r] = (int*)take((size_t)NE * 4);
        valS[r] = (float*)take((size_t)NE * 4);
    }
    int* cnt = (int*)take(NN * 4);
    int* cur = (int*)take(NN * 4);
    int* bsum = (int*)take(256 * 4);
    float* ssum = (float*)take(16 * 4);
    float* beta = (float*)take(16 * 4);

    const int GE = (NE + 255) / 256;
    const int GS = (NN + 255) / 256;
    const int GG = (NN + 63) / 64;       // 782 gemm blocks
    const int GP = (NN + 3) / 4;         // 12500 spmm blocks
    const int GC8 = (int)(NF / 8 / 256); // 3125 combine blocks
    const float invN = 1.0f / (float)NN;

    // ---- CSR build (4 relations) ----
    for (int r = 0; r < 4; ++r) {
        hipMemsetAsync(cnt, 0, NN * 4, stream);
        k_count<<<GE, 256, 0, stream>>>(dstI[r], cnt, NE);
        k_scan1<<<GS, 256, 0, stream>>>(cnt, bsum, NN);
        k_scan2<<<1, 256, 0, stream>>>(bsum, GS, rs[r], NN, NE);
        k_scan3<<<GS, 256, 0, stream>>>(cnt, bsum, rs[r], NN);
        hipMemcpyAsync(cur, rs[r], NN * 4, hipMemcpyDeviceToDevice, stream);
        k_scatter<<<GE, 256, 0, stream>>>(srcI[r], dstI[r], valI[r], cur, srcS[r], valS[r], NE);
    }
    hipMemsetAsync(ssum, 0, 16 * 4, stream);

    // ---- input conversion + weight packing ----
    k_f2b<<<(NN * 256 / 4 + 255) / 256, 256, 0, stream>>>(x_A, xAbf, NN * 256 / 4);
    k_f2b<<<(NN * 128 / 4 + 255) / 256, 256, 0, stream>>>(x_B, xBbf, NN * 128 / 4);
    {
        WPack wp;
        const float* srcs_[9] = {fc1A_w, fc1B_w, fcs_w[0], fcs_w[1], saA_w[0],
                                 saA_w[1], saB_w[0], saB_w[1], fc2_w};
        u16* dsts_[9] = {wt_fc1A, wt_fc1B, wt_fcs[0], wt_fcs[1], wt_saA[0],
                         wt_saA[1], wt_saB[0], wt_saB[1], wt_fc2};
        int Ks[9] = {256, 128, 128, 128, 128, 128, 128, 128, 128};
        int Ns[9] = {128, 128, 128, 128, 128, 128, 128, 128, 64};
        int start = 0;
        for (int i = 0; i < 9; ++i) {
            wp.d[i] = {srcs_[i], dsts_[i], Ks[i], Ns[i], start};
            start += Ks[i] * Ns[i];
        }
        k_wt<<<(start + 255) / 256, 256, 0, stream>>>(wp);
    }

    // ---- fc1 + relu ----
    k_mm<8, 8, 1, false><<<GG, 256, 0, stream>>>(xAbf, NN, wt_fc1A, fc1A_b, nullptr, xA0, nullptr);
    k_mm<4, 8, 1, false><<<GG, 256, 0, stream>>>(xBbf, NN, wt_fc1B, fc1B_b, nullptr, xB0, nullptr);

    for (int h = 0; h < 2; ++h) {
        // shared per-hop linear
        k_mm<4, 8, 0, false><<<GG, 256, 0, stream>>>(xA0, NN, wt_fcs[h], fcs_b[h], nullptr, xA1, nullptr);
        k_mm<4, 8, 0, false><<<GG, 256, 0, stream>>>(xB0, NN, wt_fcs[h], fcs_b[h], nullptr, xB1, nullptr);
        // type A: relations AA (r=0), AB (r=1)
        k_spmm<<<GP, 256, 0, stream>>>(rs[0], srcS[0], valS[0], xA1, xA1, a2I[0], h1, NN);
        k_spmm<<<GP, 256, 0, stream>>>(rs[1], srcS[1], valS[1], xB1, xA1, a2I[1], h2, NN);
        k_mm<4, 8, 2, false><<<GG, 256, 0, stream>>>(h1, NN, wt_saA[h], saA_b[h], saA_q[h], nullptr,
                                                     ssum + h * 4 + 0);
        k_mm<4, 8, 2, false><<<GG, 256, 0, stream>>>(h2, NN, wt_saA[h], saA_b[h], saA_q[h], nullptr,
                                                     ssum + h * 4 + 1);
        k_beta<<<1, 1, 0, stream>>>(ssum + h * 4 + 0, beta + h * 4 + 0, invN);
        k_combine<<<GC8, 256, 0, stream>>>(h1, h2, beta + h * 4 + 0, xA0, (int)(NF / 8));
        // type B: relations BB (r=2), BA (r=3); BA gathers the UPDATED xA
        k_spmm<<<GP, 256, 0, stream>>>(rs[2], srcS[2], valS[2], xB1, xB1, a2I[2], h1, NN);
        k_spmm<<<GP, 256, 0, stream>>>(rs[3], srcS[3], valS[3], xA0, xB1, a2I[3], h2, NN);
        k_mm<4, 8, 2, false><<<GG, 256, 0, stream>>>(h1, NN, wt_saB[h], saB_b[h], saB_q[h], nullptr,
                                                     ssum + h * 4 + 2);
        k_mm<4, 8, 2, false><<<GG, 256, 0, stream>>>(h2, NN, wt_saB[h], saB_b[h], saB_q[h], nullptr,
                                                     ssum + h * 4 + 3);
        k_beta<<<1, 1, 0, stream>>>(ssum + h * 4 + 2, beta + h * 4 + 2, invN);
        k_combine<<<GC8, 256, 0, stream>>>(h1, h2, beta + h * 4 + 2, xB0, (int)(NF / 8));
    }

    // ---- fc2 (no relu), f32 out ----
    k_mm<4, 4, 0, true><<<GG, 256, 0, stream>>>(xA0, NN, wt_fc2, fc2_b, nullptr, d_out, nullptr);
}

// Round 6
// 1086.266 us; speedup vs baseline: 1.3627x; 1.2956x over previous
//
#include <hip/hip_runtime.h>
#include <hip/hip_bf16.h>

#define NN 50000
#define NE 500000
#define DH 128
#define INV_N (1.0f / 50000.0f)

using short8 = __attribute__((ext_vector_type(8))) short;
using f32x4 = __attribute__((ext_vector_type(4))) float;
typedef unsigned short u16;

__device__ __forceinline__ float b2f(unsigned short u) {
    unsigned v = (unsigned)u << 16;
    return __builtin_bit_cast(float, v);
}
__device__ __forceinline__ unsigned short f2b(float f) {
    return __builtin_bit_cast(unsigned short, __float2bfloat16(f));
}

// ------------------------- CSR build (all 4 relations, gridDim.y = relation) ----

struct EdgePtrs {
    const int* src[4];
    const int* dst[4];
    const float* val[4];
};

__global__ void k_count4(EdgePtrs ep, int* __restrict__ cnt4) {
    int r = blockIdx.y;
    int e = blockIdx.x * 256 + threadIdx.x;
    if (e < NE) atomicAdd(&cnt4[r * NN + ep.dst[r][e]], 1);
}

__global__ void k_scan1(const int* __restrict__ cnt4, int* __restrict__ bsum4) {
    int r = blockIdx.y;
    int t = threadIdx.x;
    int idx = blockIdx.x * 256 + t;
    int v = (idx < NN) ? cnt4[r * NN + idx] : 0;
#pragma unroll
    for (int m = 1; m < 64; m <<= 1) v += __shfl_xor(v, m);
    __shared__ int w4[4];
    if ((t & 63) == 0) w4[t >> 6] = v;
    __syncthreads();
    if (t == 0) bsum4[r * 256 + blockIdx.x] = w4[0] + w4[1] + w4[2] + w4[3];
}

__global__ void k_scan2(int* __restrict__ bsum4, int nb, int* __restrict__ rs4) {
    int r = blockIdx.y;
    __shared__ int s[256];
    int t = threadIdx.x;
    s[t] = (t < nb) ? bsum4[r * 256 + t] : 0;
    __syncthreads();
#pragma unroll
    for (int off = 1; off < 256; off <<= 1) {
        int v = (t >= off) ? s[t - off] : 0;
        __syncthreads();
        s[t] += v;
        __syncthreads();
    }
    if (t < nb) bsum4[r * 256 + t] = (t == 0) ? 0 : s[t - 1];
    if (t == 0) rs4[r * (NN + 1) + NN] = NE;
}

__global__ void k_scan3(const int* __restrict__ cnt4, const int* __restrict__ bsum4,
                        int* __restrict__ rs4, int* __restrict__ cur4) {
    int r = blockIdx.y;
    __shared__ int s[256];
    int t = threadIdx.x;
    int idx = blockIdx.x * 256 + t;
    int mine = (idx < NN) ? cnt4[r * NN + idx] : 0;
    s[t] = mine;
    __syncthreads();
#pragma unroll
    for (int off = 1; off < 256; off <<= 1) {
        int v = (t >= off) ? s[t - off] : 0;
        __syncthreads();
        s[t] += v;
        __syncthreads();
    }
    if (idx < NN) {
        int start = bsum4[r * 256 + blockIdx.x] + s[t] - mine;
        rs4[r * (NN + 1) + idx] = start;
        cur4[r * NN + idx] = start;
    }
}

__global__ void k_scatter4(EdgePtrs ep, int* __restrict__ cur4, int2* __restrict__ es4) {
    int r = blockIdx.y;
    int e = blockIdx.x * 256 + threadIdx.x;
    if (e >= NE) return;
    int d = ep.dst[r][e];
    int pos = atomicAdd(&cur4[r * NN + d], 1);
    es4[(size_t)r * NE + pos] = make_int2(ep.src[r][e], __float_as_int(ep.val[r][e]));
}

// ------------------------- fp32 -> bf16 bulk convert -------------------------

__global__ void k_f2b(const float* __restrict__ src, u16* __restrict__ dst, int n4) {
    int i = blockIdx.x * 256 + threadIdx.x;
    if (i >= n4) return;
    float4 v = ((const float4*)src)[i];
    unsigned lo = (unsigned)f2b(v.x) | ((unsigned)f2b(v.y) << 16);
    unsigned hi = (unsigned)f2b(v.z) | ((unsigned)f2b(v.w) << 16);
    ((uint2*)dst)[i] = make_uint2(lo, hi);
}

// ------------------------- weight transpose + swizzle pack -------------------------
// dst: bf16 at byte ((n*K + k)*2) ^ ((n&7)<<4)  -- matches GEMM's swizzled ds_read

struct WDesc { const float* src; u16* dst; int K; int N; int start; };
struct WPack { WDesc d[9]; };

__global__ void k_wt(WPack p) {
    int gid = blockIdx.x * 256 + threadIdx.x;
#pragma unroll
    for (int i = 0; i < 9; ++i) {
        int K = p.d[i].K, N = p.d[i].N;
        int local = gid - p.d[i].start;
        if (local >= 0 && local < K * N) {
            int k = local / N;
            int n = local - k * N;
            float w = p.d[i].src[local];
            unsigned byte = ((unsigned)(n * K + k) * 2u) ^ ((unsigned)(n & 7) << 4);
            *(u16*)((char*)p.d[i].dst + byte) = f2b(w);
            return;
        }
    }
}

// ------------------------- MFMA GEMM (optionally paired via gridDim.y) ----------
// C = X@W + Bias ; MODE 0: plain, 1: relu, 2: atomicAdd(S, sum_rows(tanh(.)@Q))
template <int KT, int NF, int MODE, bool OUTF32>
__global__ __launch_bounds__(256) void k_mm(const u16* __restrict__ X0, const u16* __restrict__ X1,
                                            int M, const u16* __restrict__ WT,
                                            const float* __restrict__ Bias,
                                            const float* __restrict__ Q,
                                            void* __restrict__ O0, void* __restrict__ O1,
                                            float* __restrict__ S0, float* __restrict__ S1) {
    constexpr int K = KT * 32;
    constexpr int N = NF * 16;
    const u16* X = blockIdx.y ? X1 : X0;
    void* OutV = blockIdx.y ? O1 : O0;
    float* Sout = blockIdx.y ? S1 : S0;

    __shared__ u16 wlds[K * N];
    int t = threadIdx.x;
    constexpr int CH = K * N * 2 / 16;
    const uint4* wg = (const uint4*)WT;
    uint4* wl = (uint4*)wlds;
#pragma unroll
    for (int i = 0; i < CH / 256; ++i) wl[t + i * 256] = wg[t + i * 256];

    int l = t & 63, w = t >> 6;
    int m0 = blockIdx.x * 64 + w * 16;
    int arow = m0 + (l & 15);
    if (arow >= M) arow = M - 1;  // clamp; OOB rows masked in epilogue
    int kh = (l >> 4) * 8;

    short8 a[KT];
    const u16* xp = X + (size_t)arow * K + kh;
#pragma unroll
    for (int kt = 0; kt < KT; ++kt) a[kt] = *(const short8*)(xp + kt * 32);

    __syncthreads();

    f32x4 acc[NF];
#pragma unroll
    for (int i = 0; i < NF; ++i) acc[i] = (f32x4){0.f, 0.f, 0.f, 0.f};

    unsigned sw = (unsigned)((l & 7) << 4);
#pragma unroll
    for (int nf = 0; nf < NF; ++nf) {
        unsigned base = (unsigned)((nf * 16 + (l & 15)) * K) * 2u;
#pragma unroll
        for (int kt = 0; kt < KT; ++kt) {
            unsigned byte = (base + (unsigned)(kt * 32 + kh) * 2u) ^ sw;
            short8 b = *(const short8*)((const char*)wlds + byte);
            acc[nf] = __builtin_amdgcn_mfma_f32_16x16x32_bf16(a[kt], b, acc[nf], 0, 0, 0);
        }
    }

    // C/D layout: col=lane&15, row=(lane>>4)*4+r  [m89-verified]
    int col0 = l & 15;
    int rbase = m0 + (l >> 4) * 4;
    if (MODE == 2) {
        float tot = 0.f;
#pragma unroll
        for (int nf = 0; nf < NF; ++nf) {
            int c = nf * 16 + col0;
            float bv = Bias[c], qv = Q[c];
#pragma unroll
            for (int r = 0; r < 4; ++r)
                if (rbase + r < M) tot += tanhf(acc[nf][r] + bv) * qv;
        }
#pragma unroll
        for (int m = 1; m < 64; m <<= 1) tot += __shfl_xor(tot, m);
        if (l == 0) atomicAdd(Sout, tot);
    } else {
#pragma unroll
        for (int nf = 0; nf < NF; ++nf) {
            int c = nf * 16 + col0;
            float bv = Bias[c];
#pragma unroll
            for (int r = 0; r < 4; ++r) {
                int row = rbase + r;
                if (row >= M) continue;
                float v = acc[nf][r] + bv;
                if (MODE == 1) v = fmaxf(v, 0.f);
                if (OUTF32)
                    ((float*)OutV)[(size_t)row * N + c] = v;
                else
                    ((u16*)OutV)[(size_t)row * N + c] = f2b(v);
            }
        }
    }
}

// ------------------------- SpMM pair (bf16 gather, fp32 accum, unroll x4) -------
// out[i][:] = a2[i]*Xd[i][:] + sum_{e in row i} val[e]*Xs[src[e]][:]
struct SpmmArgs {
    const int* rs0; const int2* es0; const u16* Xs0; const u16* Xd0;
    const float* a20; u16* out0;
    const int* rs1; const int2* es1; const u16* Xs1; const u16* Xd1;
    const float* a21; u16* out1;
};

__global__ void k_spmm2(SpmmArgs p) {
    int sel = blockIdx.y;
    const int* rs = sel ? p.rs1 : p.rs0;
    const int2* es = sel ? p.es1 : p.es0;
    const u16* Xs = sel ? p.Xs1 : p.Xs0;
    const u16* Xd = sel ? p.Xd1 : p.Xd0;
    const float* a2 = sel ? p.a21 : p.a20;
    u16* Out = sel ? p.out1 : p.out0;

    int row = blockIdx.x * 4 + (threadIdx.x >> 6);
    if (row >= NN) return;
    int lane = threadIdx.x & 63;
    int e0 = rs[row], e1 = rs[row + 1];
    float a = a2[row];
    unsigned xd = *(const unsigned*)&Xd[(size_t)row * DH + lane * 2];
    float accx = a * b2f((u16)xd);
    float accy = a * b2f((u16)(xd >> 16));

    int e = e0;
    for (; e + 4 <= e1; e += 4) {
        int2 p0 = es[e], p1 = es[e + 1], p2 = es[e + 2], p3 = es[e + 3];
        unsigned x0 = *(const unsigned*)&Xs[(size_t)p0.x * DH + lane * 2];
        unsigned x1 = *(const unsigned*)&Xs[(size_t)p1.x * DH + lane * 2];
        unsigned x2 = *(const unsigned*)&Xs[(size_t)p2.x * DH + lane * 2];
        unsigned x3 = *(const unsigned*)&Xs[(size_t)p3.x * DH + lane * 2];
        float v0 = __int_as_float(p0.y), v1 = __int_as_float(p1.y);
        float v2 = __int_as_float(p2.y), v3 = __int_as_float(p3.y);
        accx += v0 * b2f((u16)x0);
        accy += v0 * b2f((u16)(x0 >> 16));
        accx += v1 * b2f((u16)x1);
        accy += v1 * b2f((u16)(x1 >> 16));
        accx += v2 * b2f((u16)x2);
        accy += v2 * b2f((u16)(x2 >> 16));
        accx += v3 * b2f((u16)x3);
        accy += v3 * b2f((u16)(x3 >> 16));
    }
    for (; e < e1; ++e) {
        int2 pe = es[e];
        float v = __int_as_float(pe.y);
        unsigned xv = *(const unsigned*)&Xs[(size_t)pe.x * DH + lane * 2];
        accx += v * b2f((u16)xv);
        accy += v * b2f((u16)(xv >> 16));
    }
    unsigned o = (unsigned)f2b(accx) | ((unsigned)f2b(accy) << 16);
    *(unsigned*)&Out[(size_t)row * DH + lane * 2] = o;
}

// ------------------------- combine (inline beta softmax) -------------------------

__global__ void k_combine(const u16* __restrict__ h1, const u16* __restrict__ h2,
                          const float* __restrict__ ssum2, u16* __restrict__ out, int n8) {
    int i = blockIdx.x * 256 + threadIdx.x;
    if (i >= n8) return;
    float s0 = ssum2[0] * INV_N, s1 = ssum2[1] * INV_N;
    float m = fmaxf(s0, s1);
    float ea = __expf(s0 - m), eb = __expf(s1 - m);
    float inv = 1.0f / (ea + eb);
    float b0 = ea * inv, b1 = eb * inv;
    short8 A = ((const short8*)h1)[i];
    short8 B = ((const short8*)h2)[i];
    short8 O;
#pragma unroll
    for (int j = 0; j < 8; ++j) {
        float v = b0 * b2f((u16)A[j]) + b1 * b2f((u16)B[j]);
        O[j] = (short)f2b(fmaxf(v, 0.f));
    }
    ((short8*)out)[i] = O;
}

// ------------------------- launch -------------------------

extern "C" void kernel_launch(void* const* d_in, const int* in_sizes, int n_in, void* d_out,
                              int out_size, void* d_ws, size_t ws_size, hipStream_t stream) {
    (void)in_sizes; (void)n_in; (void)out_size; (void)ws_size;

    const float* x_A = (const float*)d_in[0];
    const float* x_B = (const float*)d_in[1];
    EdgePtrs ep;
    const float* a2I[4];
    for (int r = 0; r < 4; ++r) {  // AA, AB, BB, BA
        ep.src[r] = (const int*)d_in[2 + r * 4];
        ep.dst[r] = (const int*)d_in[3 + r * 4];
        ep.val[r] = (const float*)d_in[4 + r * 4];
        a2I[r] = (const float*)d_in[5 + r * 4];
    }
    const float* fc1A_w = (const float*)d_in[18];
    const float* fc1A_b = (const float*)d_in[19];
    const float* fc1B_w = (const float*)d_in[20];
    const float* fc1B_b = (const float*)d_in[21];
    const float* fcs_w[2] = {(const float*)d_in[22], (const float*)d_in[30]};
    const float* fcs_b[2] = {(const float*)d_in[23], (const float*)d_in[31]};
    const float* saA_w[2] = {(const float*)d_in[24], (const float*)d_in[32]};
    const float* saA_b[2] = {(const float*)d_in[25], (const float*)d_in[33]};
    const float* saA_q[2] = {(const float*)d_in[26], (const float*)d_in[34]};
    const float* saB_w[2] = {(const float*)d_in[27], (const float*)d_in[35]};
    const float* saB_b[2] = {(const float*)d_in[28], (const float*)d_in[36]};
    const float* saB_q[2] = {(const float*)d_in[29], (const float*)d_in[37]};
    const float* fc2_w = (const float*)d_in[38];
    const float* fc2_b = (const float*)d_in[39];

    char* p = (char*)d_ws;
    auto take = [&](size_t bytes) -> void* {
        void* r = (void*)p;
        p += (bytes + 255) & ~(size_t)255;
        return r;
    };
    const size_t NF = (size_t)NN * DH;
    u16* xAbf = (u16*)take((size_t)NN * 256 * 2);
    u16* xBbf = (u16*)take((size_t)NN * 128 * 2);
    u16* xA0 = (u16*)take(NF * 2);
    u16* xA1 = (u16*)take(NF * 2);
    u16* xB0 = (u16*)take(NF * 2);
    u16* xB1 = (u16*)take(NF * 2);
    u16* h1 = (u16*)take(NF * 2);
    u16* h2 = (u16*)take(NF * 2);
    u16* wt_fc1A = (u16*)take(256 * 128 * 2);
    u16* wt_fc1B = (u16*)take(128 * 128 * 2);
    u16* wt_fcs[2] = {(u16*)take(128 * 128 * 2), (u16*)take(128 * 128 * 2)};
    u16* wt_saA[2] = {(u16*)take(128 * 128 * 2), (u16*)take(128 * 128 * 2)};
    u16* wt_saB[2] = {(u16*)take(128 * 128 * 2), (u16*)take(128 * 128 * 2)};
    u16* wt_fc2 = (u16*)take(128 * 64 * 2);
    int* rs4 = (int*)take((size_t)(NN + 1) * 4 * 4);
    int* cur4 = (int*)take((size_t)NN * 4 * 4);
    int* cnt4 = (int*)take((size_t)NN * 4 * 4);
    int* bsum4 = (int*)take(256 * 4 * 4);
    int2* es4 = (int2*)take((size_t)NE * 4 * 8);
    float* ssum = (float*)take(16 * 4);

    const int GE = (NE + 255) / 256;
    const int GS = (NN + 255) / 256;      // 196
    const int GG = (NN + 63) / 64;        // 782
    const int GP = (NN + 3) / 4;          // 12500
    const int GC8 = (int)(NF / 8 / 256);  // 3125

    const int* rsR[4];
    const int2* esR[4];
    for (int r = 0; r < 4; ++r) {
        rsR[r] = rs4 + r * (NN + 1);
        esR[r] = es4 + (size_t)r * NE;
    }

    // ---- fused CSR build ----
    hipMemsetAsync(cnt4, 0, (size_t)NN * 4 * 4, stream);
    hipMemsetAsync(ssum, 0, 16 * 4, stream);
    k_count4<<<dim3(GE, 4), 256, 0, stream>>>(ep, cnt4);
    k_scan1<<<dim3(GS, 4), 256, 0, stream>>>(cnt4, bsum4);
    k_scan2<<<dim3(1, 4), 256, 0, stream>>>(bsum4, GS, rs4);
    k_scan3<<<dim3(GS, 4), 256, 0, stream>>>(cnt4, bsum4, rs4, cur4);
    k_scatter4<<<dim3(GE, 4), 256, 0, stream>>>(ep, cur4, es4);

    // ---- input conversion + weight packing ----
    k_f2b<<<(NN * 256 / 4 + 255) / 256, 256, 0, stream>>>(x_A, xAbf, NN * 256 / 4);
    k_f2b<<<(NN * 128 / 4 + 255) / 256, 256, 0, stream>>>(x_B, xBbf, NN * 128 / 4);
    {
        WPack wp;
        const float* srcs_[9] = {fc1A_w, fc1B_w, fcs_w[0], fcs_w[1], saA_w[0],
                                 saA_w[1], saB_w[0], saB_w[1], fc2_w};
        u16* dsts_[9] = {wt_fc1A, wt_fc1B, wt_fcs[0], wt_fcs[1], wt_saA[0],
                         wt_saA[1], wt_saB[0], wt_saB[1], wt_fc2};
        int Ks[9] = {256, 128, 128, 128, 128, 128, 128, 128, 128};
        int Ns[9] = {128, 128, 128, 128, 128, 128, 128, 128, 64};
        int start = 0;
        for (int i = 0; i < 9; ++i) {
            wp.d[i] = {srcs_[i], dsts_[i], Ks[i], Ns[i], start};
            start += Ks[i] * Ns[i];
        }
        k_wt<<<(start + 255) / 256, 256, 0, stream>>>(wp);
    }

    // ---- fc1 + relu ----
    k_mm<8, 8, 1, false><<<dim3(GG, 1), 256, 0, stream>>>(xAbf, xAbf, NN, wt_fc1A, fc1A_b,
                                                          nullptr, xA0, xA0, nullptr, nullptr);
    k_mm<4, 8, 1, false><<<dim3(GG, 1), 256, 0, stream>>>(xBbf, xBbf, NN, wt_fc1B, fc1B_b,
                                                          nullptr, xB0, xB0, nullptr, nullptr);

    for (int h = 0; h < 2; ++h) {
        // shared per-hop linear: xA1 = xA0@fcs+b, xB1 = xB0@fcs+b (one dispatch)
        k_mm<4, 8, 0, false><<<dim3(GG, 2), 256, 0, stream>>>(xA0, xB0, NN, wt_fcs[h], fcs_b[h],
                                                              nullptr, xA1, xB1, nullptr, nullptr);
        // type A: AA (r=0) -> h1, AB (r=1) -> h2
        {
            SpmmArgs sa = {rsR[0], esR[0], xA1, xA1, a2I[0], h1,
                           rsR[1], esR[1], xB1, xA1, a2I[1], h2};
            k_spmm2<<<dim3(GP, 2), 256, 0, stream>>>(sa);
        }
        k_mm<4, 8, 2, false><<<dim3(GG, 2), 256, 0, stream>>>(h1, h2, NN, wt_saA[h], saA_b[h],
                                                              saA_q[h], nullptr, nullptr,
                                                              ssum + h * 4 + 0, ssum + h * 4 + 1);
        k_combine<<<GC8, 256, 0, stream>>>(h1, h2, ssum + h * 4 + 0, xA0, (int)(NF / 8));
        // type B: BB (r=2) -> h1, BA (r=3, gathers UPDATED xA0) -> h2
        {
            SpmmArgs sb = {rsR[2], esR[2], xB1, xB1, a2I[2], h1,
                           rsR[3], esR[3], xA0, xB1, a2I[3], h2};
            k_spmm2<<<dim3(GP, 2), 256, 0, stream>>>(sb);
        }
        k_mm<4, 8, 2, false><<<dim3(GG, 2), 256, 0, stream>>>(h1, h2, NN, wt_saB[h], saB_b[h],
                                                              saB_q[h], nullptr, nullptr,
                                                              ssum + h * 4 + 2, ssum + h * 4 + 3);
        k_combine<<<GC8, 256, 0, stream>>>(h1, h2, ssum + h * 4 + 2, xB0, (int)(NF / 8));
    }

    // ---- fc2 (no relu), f32 out ----
    k_mm<4, 4, 0, true><<<dim3(GG, 1), 256, 0, stream>>>(xA0, xA0, NN, wt_fc2, fc2_b, nullptr,
                                                         d_out, d_out, nullptr, nullptr);
}

// Round 7
// 922.515 us; speedup vs baseline: 1.6046x; 1.1775x over previous
//
#include <hip/hip_runtime.h>
#include <hip/hip_bf16.h>

#define NN 50000
#define NE 500000
#define DH 128
#define INV_N (1.0f / 50000.0f)
#define NBUCK 98      // ceil(50000 / 512)
#define BSH 9         // bucket = dst >> 9
#define T1 4096       // edges per multisplit tile
#define NT1 ((NE + T1 - 1) / T1)  // 123

using short8 = __attribute__((ext_vector_type(8))) short;
using f32x4 = __attribute__((ext_vector_type(4))) float;
typedef unsigned short u16;

__device__ __forceinline__ float b2f(unsigned short u) {
    unsigned v = (unsigned)u << 16;
    return __builtin_bit_cast(float, v);
}
__device__ __forceinline__ unsigned short f2b(float f) {
    return __builtin_bit_cast(unsigned short, __float2bfloat16(f));
}

struct EdgePtrs {
    const int* src[4];
    const int* dst[4];
    const float* val[4];
};

// ---------------- CSR build: bucketed counting sort (line-friendly writes) ------

// pass 0: per-bucket totals via LDS histogram
__global__ void k_bhist(EdgePtrs ep, int* __restrict__ btot) {
    int r = blockIdx.y;
    const int* dst = ep.dst[r];
    __shared__ int h[NBUCK];
    int t = threadIdx.x;
    if (t < NBUCK) h[t] = 0;
    __syncthreads();
    int e0 = blockIdx.x * T1;
#pragma unroll
    for (int i = 0; i < T1 / 256; ++i) {
        int e = e0 + i * 256 + t;
        if (e < NE) atomicAdd(&h[dst[e] >> BSH], 1);
    }
    __syncthreads();
    if (t < NBUCK && h[t] > 0) atomicAdd(&btot[r * NBUCK + t], h[t]);
}

// pass 0.5: exclusive scan of bucket totals -> bases + cursors
__global__ void k_bscan(const int* __restrict__ btot, int* __restrict__ bbase,
                        int* __restrict__ bcur) {
    __shared__ int s[128];
    int t = threadIdx.x;
    for (int r = 0; r < 4; ++r) {
        int v = (t < NBUCK) ? btot[r * NBUCK + t] : 0;
        if (t < 128) s[t] = v;
        __syncthreads();
        for (int off = 1; off < 128; off <<= 1) {
            int u = (t >= off && t < 128) ? s[t - off] : 0;
            __syncthreads();
            if (t < 128) s[t] += u;
            __syncthreads();
        }
        if (t < NBUCK) {
            int ex = s[t] - v;
            bbase[r * NBUCK + t] = ex;
            bcur[r * NBUCK + t] = ex;
        }
        __syncthreads();
    }
}

// pass 1: multisplit into bucket-contiguous regions; LDS grouping so global
// writes are ~336B contiguous runs (kills cross-XCD line sharing)
__global__ __launch_bounds__(256) void k_msplit(EdgePtrs ep, int* __restrict__ bcur,
                                                int2* __restrict__ esb) {
    int r = blockIdx.y;
    const int* src = ep.src[r];
    const int* dst = ep.dst[r];
    const float* val = ep.val[r];
    __shared__ int2 eb[T1];
    __shared__ int hist[128], lofs[128], lcur[128], sc[128], gbase[NBUCK];
    int t = threadIdx.x;
    int e0 = blockIdx.x * T1;
    int total = NE - e0;
    if (total > T1) total = T1;

    int sreg[T1 / 256], dreg[T1 / 256];
    float vreg[T1 / 256];
#pragma unroll
    for (int i = 0; i < T1 / 256; ++i) {
        int e = e0 + i * 256 + t;
        bool ok = e < NE;
        sreg[i] = ok ? src[e] : 0;
        dreg[i] = ok ? dst[e] : -1;
        vreg[i] = ok ? val[e] : 0.f;
    }
    if (t < 128) { hist[t] = 0; lcur[t] = 0; }
    __syncthreads();
#pragma unroll
    for (int i = 0; i < T1 / 256; ++i)
        if (dreg[i] >= 0) atomicAdd(&hist[dreg[i] >> BSH], 1);
    __syncthreads();
    if (t < 128) sc[t] = hist[t];
    __syncthreads();
    for (int off = 1; off < 128; off <<= 1) {
        int u = (t >= off && t < 128) ? sc[t - off] : 0;
        __syncthreads();
        if (t < 128) sc[t] += u;
        __syncthreads();
    }
    if (t < 128) lofs[t] = sc[t] - hist[t];
    __syncthreads();
#pragma unroll
    for (int i = 0; i < T1 / 256; ++i) {
        if (dreg[i] >= 0) {
            int b = dreg[i] >> BSH;
            int pos = lofs[b] + atomicAdd(&lcur[b], 1);
            eb[pos] = make_int2((int)(((unsigned)dreg[i] << 16) | (unsigned)sreg[i]),
                                __float_as_int(vreg[i]));
        }
    }
    __syncthreads();
    if (t < NBUCK && hist[t] > 0) gbase[t] = atomicAdd(&bcur[r * NBUCK + t], hist[t]);
    __syncthreads();
    for (int j = t; j < total; j += 256) {
        int2 rec = eb[j];
        int b = (int)((unsigned)rec.x >> (16 + BSH));
        esb[(size_t)r * NE + gbase[b] + (j - lofs[b])] = rec;
    }
}

// pass 2: per-bucket local counting sort -> final CSR (rs + dst-grouped edges).
// All writes land in this block's OWN contiguous region -> no line sharing.
__global__ __launch_bounds__(256) void k_blocal(const int2* __restrict__ esb,
                                                const int* __restrict__ btot,
                                                const int* __restrict__ bbase,
                                                int* __restrict__ rs4,
                                                int2* __restrict__ es4) {
    int r = blockIdx.y, b = blockIdx.x;
    int base = bbase[r * NBUCK + b];
    int cnt = btot[r * NBUCK + b];
    int d0 = b << BSH;
    int dlim = NN - d0;
    if (dlim > (1 << BSH)) dlim = 1 << BSH;
    __shared__ int h[512], pr[512], cur[512], ps[256];
    int t = threadIdx.x;
    h[t] = 0; h[t + 256] = 0;
    cur[t] = 0; cur[t + 256] = 0;
    __syncthreads();
    const int2* ein = esb + (size_t)r * NE + base;
    for (int j = t; j < cnt; j += 256)
        atomicAdd(&h[(int)((unsigned)ein[j].x >> 16) - d0], 1);
    __syncthreads();
    int a0 = h[2 * t], a1 = h[2 * t + 1];
    ps[t] = a0 + a1;
    __syncthreads();
    for (int off = 1; off < 256; off <<= 1) {
        int u = (t >= off) ? ps[t - off] : 0;
        __syncthreads();
        ps[t] += u;
        __syncthreads();
    }
    int ex = ps[t] - (a0 + a1);
    pr[2 * t] = ex;
    pr[2 * t + 1] = ex + a0;
    __syncthreads();
    for (int dl = t; dl < dlim; dl += 256) rs4[r * (NN + 1) + d0 + dl] = base + pr[dl];
    if (b == NBUCK - 1 && t == 0) rs4[r * (NN + 1) + NN] = NE;
    for (int j = t; j < cnt; j += 256) {
        int2 rec = ein[j];
        int dl = (int)((unsigned)rec.x >> 16) - d0;
        int k = atomicAdd(&cur[dl], 1);
        es4[(size_t)r * NE + base + pr[dl] + k] = make_int2(rec.x & 0xFFFF, rec.y);
    }
}

// ------------------------- fp32 -> bf16 bulk convert -------------------------

__global__ void k_f2b(const float* __restrict__ src, u16* __restrict__ dst, int n4) {
    int i = blockIdx.x * 256 + threadIdx.x;
    if (i >= n4) return;
    float4 v = ((const float4*)src)[i];
    unsigned lo = (unsigned)f2b(v.x) | ((unsigned)f2b(v.y) << 16);
    unsigned hi = (unsigned)f2b(v.z) | ((unsigned)f2b(v.w) << 16);
    ((uint2*)dst)[i] = make_uint2(lo, hi);
}

// ------------------------- weight transpose + swizzle pack -------------------------
// dst: bf16 at byte ((n*K + k)*2) ^ ((n&7)<<4)  -- matches GEMM's swizzled ds_read

struct WDesc { const float* src; u16* dst; int K; int N; int start; };
struct WPack { WDesc d[9]; };

__global__ void k_wt(WPack p) {
    int gid = blockIdx.x * 256 + threadIdx.x;
#pragma unroll
    for (int i = 0; i < 9; ++i) {
        int K = p.d[i].K, N = p.d[i].N;
        int local = gid - p.d[i].start;
        if (local >= 0 && local < K * N) {
            int k = local / N;
            int n = local - k * N;
            float w = p.d[i].src[local];
            unsigned byte = ((unsigned)(n * K + k) * 2u) ^ ((unsigned)(n & 7) << 4);
            *(u16*)((char*)p.d[i].dst + byte) = f2b(w);
            return;
        }
    }
}

// ------------------------- MFMA GEMM (optionally paired via gridDim.y) ----------
// C = X@W + Bias ; MODE 0: plain, 1: relu, 2: atomicAdd(S, sum_rows(tanh(.)@Q))
template <int KT, int NF, int MODE, bool OUTF32>
__global__ __launch_bounds__(256) void k_mm(const u16* __restrict__ X0, const u16* __restrict__ X1,
                                            int M, const u16* __restrict__ WT,
                                            const float* __restrict__ Bias,
                                            const float* __restrict__ Q,
                                            void* __restrict__ O0, void* __restrict__ O1,
                                            float* __restrict__ S0, float* __restrict__ S1) {
    constexpr int K = KT * 32;
    constexpr int N = NF * 16;
    const u16* X = blockIdx.y ? X1 : X0;
    void* OutV = blockIdx.y ? O1 : O0;
    float* Sout = blockIdx.y ? S1 : S0;

    __shared__ u16 wlds[K * N];
    int t = threadIdx.x;
    constexpr int CH = K * N * 2 / 16;
    const uint4* wg = (const uint4*)WT;
    uint4* wl = (uint4*)wlds;
#pragma unroll
    for (int i = 0; i < CH / 256; ++i) wl[t + i * 256] = wg[t + i * 256];

    int l = t & 63, w = t >> 6;
    int m0 = blockIdx.x * 64 + w * 16;
    int arow = m0 + (l & 15);
    if (arow >= M) arow = M - 1;  // clamp; OOB rows masked in epilogue
    int kh = (l >> 4) * 8;

    short8 a[KT];
    const u16* xp = X + (size_t)arow * K + kh;
#pragma unroll
    for (int kt = 0; kt < KT; ++kt) a[kt] = *(const short8*)(xp + kt * 32);

    __syncthreads();

    f32x4 acc[NF];
#pragma unroll
    for (int i = 0; i < NF; ++i) acc[i] = (f32x4){0.f, 0.f, 0.f, 0.f};

    unsigned sw = (unsigned)((l & 7) << 4);
#pragma unroll
    for (int nf = 0; nf < NF; ++nf) {
        unsigned base = (unsigned)((nf * 16 + (l & 15)) * K) * 2u;
#pragma unroll
        for (int kt = 0; kt < KT; ++kt) {
            unsigned byte = (base + (unsigned)(kt * 32 + kh) * 2u) ^ sw;
            short8 b = *(const short8*)((const char*)wlds + byte);
            acc[nf] = __builtin_amdgcn_mfma_f32_16x16x32_bf16(a[kt], b, acc[nf], 0, 0, 0);
        }
    }

    // C/D layout: col=lane&15, row=(lane>>4)*4+r  [m89-verified]
    int col0 = l & 15;
    int rbase = m0 + (l >> 4) * 4;
    if (MODE == 2) {
        float tot = 0.f;
#pragma unroll
        for (int nf = 0; nf < NF; ++nf) {
            int c = nf * 16 + col0;
            float bv = Bias[c], qv = Q[c];
#pragma unroll
            for (int r = 0; r < 4; ++r)
                if (rbase + r < M) tot += tanhf(acc[nf][r] + bv) * qv;
        }
#pragma unroll
        for (int m = 1; m < 64; m <<= 1) tot += __shfl_xor(tot, m);
        if (l == 0) atomicAdd(Sout, tot);
    } else {
#pragma unroll
        for (int nf = 0; nf < NF; ++nf) {
            int c = nf * 16 + col0;
            float bv = Bias[c];
#pragma unroll
            for (int r = 0; r < 4; ++r) {
                int row = rbase + r;
                if (row >= M) continue;
                float v = acc[nf][r] + bv;
                if (MODE == 1) v = fmaxf(v, 0.f);
                if (OUTF32)
                    ((float*)OutV)[(size_t)row * N + c] = v;
                else
                    ((u16*)OutV)[(size_t)row * N + c] = f2b(v);
            }
        }
    }
}

// ------------------------- SpMM pair (bf16 gather, fp32 accum, unroll x4) -------
// out[i][:] = a2[i]*Xd[i][:] + sum_{e in row i} val[e]*Xs[src[e]][:]
struct SpmmArgs {
    const int* rs0; const int2* es0; const u16* Xs0; const u16* Xd0;
    const float* a20; u16* out0;
    const int* rs1; const int2* es1; const u16* Xs1; const u16* Xd1;
    const float* a21; u16* out1;
};

__global__ void k_spmm2(SpmmArgs p) {
    int sel = blockIdx.y;
    const int* rs = sel ? p.rs1 : p.rs0;
    const int2* es = sel ? p.es1 : p.es0;
    const u16* Xs = sel ? p.Xs1 : p.Xs0;
    const u16* Xd = sel ? p.Xd1 : p.Xd0;
    const float* a2 = sel ? p.a21 : p.a20;
    u16* Out = sel ? p.out1 : p.out0;

    int row = blockIdx.x * 4 + (threadIdx.x >> 6);
    if (row >= NN) return;
    int lane = threadIdx.x & 63;
    int e0 = rs[row], e1 = rs[row + 1];
    float a = a2[row];
    unsigned xd = *(const unsigned*)&Xd[(size_t)row * DH + lane * 2];
    float accx = a * b2f((u16)xd);
    float accy = a * b2f((u16)(xd >> 16));

    int e = e0;
    for (; e + 4 <= e1; e += 4) {
        int2 p0 = es[e], p1 = es[e + 1], p2 = es[e + 2], p3 = es[e + 3];
        unsigned x0 = *(const unsigned*)&Xs[(size_t)p0.x * DH + lane * 2];
        unsigned x1 = *(const unsigned*)&Xs[(size_t)p1.x * DH + lane * 2];
        unsigned x2 = *(const unsigned*)&Xs[(size_t)p2.x * DH + lane * 2];
        unsigned x3 = *(const unsigned*)&Xs[(size_t)p3.x * DH + lane * 2];
        float v0 = __int_as_float(p0.y), v1 = __int_as_float(p1.y);
        float v2 = __int_as_float(p2.y), v3 = __int_as_float(p3.y);
        accx += v0 * b2f((u16)x0);
        accy += v0 * b2f((u16)(x0 >> 16));
        accx += v1 * b2f((u16)x1);
        accy += v1 * b2f((u16)(x1 >> 16));
        accx += v2 * b2f((u16)x2);
        accy += v2 * b2f((u16)(x2 >> 16));
        accx += v3 * b2f((u16)x3);
        accy += v3 * b2f((u16)(x3 >> 16));
    }
    for (; e < e1; ++e) {
        int2 pe = es[e];
        float v = __int_as_float(pe.y);
        unsigned xv = *(const unsigned*)&Xs[(size_t)pe.x * DH + lane * 2];
        accx += v * b2f((u16)xv);
        accy += v * b2f((u16)(xv >> 16));
    }
    unsigned o = (unsigned)f2b(accx) | ((unsigned)f2b(accy) << 16);
    *(unsigned*)&Out[(size_t)row * DH + lane * 2] = o;
}

// ------------------------- combine (inline beta softmax) -------------------------

__global__ void k_combine(const u16* __restrict__ h1, const u16* __restrict__ h2,
                          const float* __restrict__ ssum2, u16* __restrict__ out, int n8) {
    int i = blockIdx.x * 256 + threadIdx.x;
    if (i >= n8) return;
    float s0 = ssum2[0] * INV_N, s1 = ssum2[1] * INV_N;
    float m = fmaxf(s0, s1);
    float ea = __expf(s0 - m), eb = __expf(s1 - m);
    float inv = 1.0f / (ea + eb);
    float b0 = ea * inv, b1 = eb * inv;
    short8 A = ((const short8*)h1)[i];
    short8 B = ((const short8*)h2)[i];
    short8 O;
#pragma unroll
    for (int j = 0; j < 8; ++j) {
        float v = b0 * b2f((u16)A[j]) + b1 * b2f((u16)B[j]);
        O[j] = (short)f2b(fmaxf(v, 0.f));
    }
    ((short8*)out)[i] = O;
}

// ------------------------- launch -------------------------

extern "C" void kernel_launch(void* const* d_in, const int* in_sizes, int n_in, void* d_out,
                              int out_size, void* d_ws, size_t ws_size, hipStream_t stream) {
    (void)in_sizes; (void)n_in; (void)out_size; (void)ws_size;

    const float* x_A = (const float*)d_in[0];
    const float* x_B = (const float*)d_in[1];
    EdgePtrs ep;
    const float* a2I[4];
    for (int r = 0; r < 4; ++r) {  // AA, AB, BB, BA
        ep.src[r] = (const int*)d_in[2 + r * 4];
        ep.dst[r] = (const int*)d_in[3 + r * 4];
        ep.val[r] = (const float*)d_in[4 + r * 4];
        a2I[r] = (const float*)d_in[5 + r * 4];
    }
    const float* fc1A_w = (const float*)d_in[18];
    const float* fc1A_b = (const float*)d_in[19];
    const float* fc1B_w = (const float*)d_in[20];
    const float* fc1B_b = (const float*)d_in[21];
    const float* fcs_w[2] = {(const float*)d_in[22], (const float*)d_in[30]};
    const float* fcs_b[2] = {(const float*)d_in[23], (const float*)d_in[31]};
    const float* saA_w[2] = {(const float*)d_in[24], (const float*)d_in[32]};
    const float* saA_b[2] = {(const float*)d_in[25], (const float*)d_in[33]};
    const float* saA_q[2] = {(const float*)d_in[26], (const float*)d_in[34]};
    const float* saB_w[2] = {(const float*)d_in[27], (const float*)d_in[35]};
    const float* saB_b[2] = {(const float*)d_in[28], (const float*)d_in[36]};
    const float* saB_q[2] = {(const float*)d_in[29], (const float*)d_in[37]};
    const float* fc2_w = (const float*)d_in[38];
    const float* fc2_b = (const float*)d_in[39];

    char* p = (char*)d_ws;
    auto take = [&](size_t bytes) -> void* {
        void* r = (void*)p;
        p += (bytes + 255) & ~(size_t)255;
        return r;
    };
    const size_t NF = (size_t)NN * DH;
    u16* xAbf = (u16*)take((size_t)NN * 256 * 2);
    u16* xBbf = (u16*)take((size_t)NN * 128 * 2);
    u16* xA0 = (u16*)take(NF * 2);
    u16* xA1 = (u16*)take(NF * 2);
    u16* xB0 = (u16*)take(NF * 2);
    u16* xB1 = (u16*)take(NF * 2);
    u16* h1 = (u16*)take(NF * 2);
    u16* h2 = (u16*)take(NF * 2);
    u16* wt_fc1A = (u16*)take(256 * 128 * 2);
    u16* wt_fc1B = (u16*)take(128 * 128 * 2);
    u16* wt_fcs[2] = {(u16*)take(128 * 128 * 2), (u16*)take(128 * 128 * 2)};
    u16* wt_saA[2] = {(u16*)take(128 * 128 * 2), (u16*)take(128 * 128 * 2)};
    u16* wt_saB[2] = {(u16*)take(128 * 128 * 2), (u16*)take(128 * 128 * 2)};
    u16* wt_fc2 = (u16*)take(128 * 64 * 2);
    int* rs4 = (int*)take((size_t)(NN + 1) * 4 * 4);
    int2* es4 = (int2*)take((size_t)NE * 4 * 8);
    int2* esb = (int2*)take((size_t)NE * 4 * 8);
    int* btot = (int*)take(NBUCK * 4 * 4);
    int* bbase = (int*)take(NBUCK * 4 * 4);
    int* bcur = (int*)take(NBUCK * 4 * 4);
    float* ssum = (float*)take(16 * 4);

    const int GG = (NN + 63) / 64;        // 782
    const int GP = (NN + 3) / 4;          // 12500
    const int GC8 = (int)(NF / 8 / 256);  // 3125

    const int* rsR[4];
    const int2* esR[4];
    for (int r = 0; r < 4; ++r) {
        rsR[r] = rs4 + r * (NN + 1);
        esR[r] = es4 + (size_t)r * NE;
    }

    // ---- CSR build: bucketed counting sort ----
    hipMemsetAsync(btot, 0, NBUCK * 4 * 4, stream);
    hipMemsetAsync(ssum, 0, 16 * 4, stream);
    k_bhist<<<dim3(NT1, 4), 256, 0, stream>>>(ep, btot);
    k_bscan<<<1, 256, 0, stream>>>(btot, bbase, bcur);
    k_msplit<<<dim3(NT1, 4), 256, 0, stream>>>(ep, bcur, esb);
    k_blocal<<<dim3(NBUCK, 4), 256, 0, stream>>>(esb, btot, bbase, rs4, es4);

    // ---- input conversion + weight packing ----
    k_f2b<<<(NN * 256 / 4 + 255) / 256, 256, 0, stream>>>(x_A, xAbf, NN * 256 / 4);
    k_f2b<<<(NN * 128 / 4 + 255) / 256, 256, 0, stream>>>(x_B, xBbf, NN * 128 / 4);
    {
        WPack wp;
        const float* srcs_[9] = {fc1A_w, fc1B_w, fcs_w[0], fcs_w[1], saA_w[0],
                                 saA_w[1], saB_w[0], saB_w[1], fc2_w};
        u16* dsts_[9] = {wt_fc1A, wt_fc1B, wt_fcs[0], wt_fcs[1], wt_saA[0],
                         wt_saA[1], wt_saB[0], wt_saB[1], wt_fc2};
        int Ks[9] = {256, 128, 128, 128, 128, 128, 128, 128, 128};
        int Ns[9] = {128, 128, 128, 128, 128, 128, 128, 128, 64};
        int start = 0;
        for (int i = 0; i < 9; ++i) {
            wp.d[i] = {srcs_[i], dsts_[i], Ks[i], Ns[i], start};
            start += Ks[i] * Ns[i];
        }
        k_wt<<<(start + 255) / 256, 256, 0, stream>>>(wp);
    }

    // ---- fc1 + relu ----
    k_mm<8, 8, 1, false><<<dim3(GG, 1), 256, 0, stream>>>(xAbf, xAbf, NN, wt_fc1A, fc1A_b,
                                                          nullptr, xA0, xA0, nullptr, nullptr);
    k_mm<4, 8, 1, false><<<dim3(GG, 1), 256, 0, stream>>>(xBbf, xBbf, NN, wt_fc1B, fc1B_b,
                                                          nullptr, xB0, xB0, nullptr, nullptr);

    for (int h = 0; h < 2; ++h) {
        // shared per-hop linear: xA1 = xA0@fcs+b, xB1 = xB0@fcs+b (one dispatch)
        k_mm<4, 8, 0, false><<<dim3(GG, 2), 256, 0, stream>>>(xA0, xB0, NN, wt_fcs[h], fcs_b[h],
                                                              nullptr, xA1, xB1, nullptr, nullptr);
        // type A: AA (r=0) -> h1, AB (r=1) -> h2
        {
            SpmmArgs sa = {rsR[0], esR[0], xA1, xA1, a2I[0], h1,
                           rsR[1], esR[1], xB1, xA1, a2I[1], h2};
            k_spmm2<<<dim3(GP, 2), 256, 0, stream>>>(sa);
        }
        k_mm<4, 8, 2, false><<<dim3(GG, 2), 256, 0, stream>>>(h1, h2, NN, wt_saA[h], saA_b[h],
                                                              saA_q[h], nullptr, nullptr,
                                                              ssum + h * 4 + 0, ssum + h * 4 + 1);
        k_combine<<<GC8, 256, 0, stream>>>(h1, h2, ssum + h * 4 + 0, xA0, (int)(NF / 8));
        // type B: BB (r=2) -> h1, BA (r=3, gathers UPDATED xA0) -> h2
        {
            SpmmArgs sb = {rsR[2], esR[2], xB1, xB1, a2I[2], h1,
                           rsR[3], esR[3], xA0, xB1, a2I[3], h2};
            k_spmm2<<<dim3(GP, 2), 256, 0, stream>>>(sb);
        }
        k_mm<4, 8, 2, false><<<dim3(GG, 2), 256, 0, stream>>>(h1, h2, NN, wt_saB[h], saB_b[h],
                                                              saB_q[h], nullptr, nullptr,
                                                              ssum + h * 4 + 2, ssum + h * 4 + 3);
        k_combine<<<GC8, 256, 0, stream>>>(h1, h2, ssum + h * 4 + 2, xB0, (int)(NF / 8));
    }

    // ---- fc2 (no relu), f32 out ----
    k_mm<4, 4, 0, true><<<dim3(GG, 1), 256, 0, stream>>>(xA0, xA0, NN, wt_fc2, fc2_b, nullptr,
                                                         d_out, d_out, nullptr, nullptr);
}

// Round 8
// 647.590 us; speedup vs baseline: 2.2858x; 1.4245x over previous
//
#include <hip/hip_runtime.h>
#include <hip/hip_bf16.h>

#define NN 50000
#define NE 500000
#define DH 128
#define INV_N (1.0f / 50000.0f)
#define NBUCK 98      // ceil(50000 / 512)
#define BSH 9         // bucket = dst >> 9
#define T1 4096       // edges per multisplit tile
#define NT1 ((NE + T1 - 1) / T1)  // 123
#define GGC 782       // (NN + 63) / 64 gemm blocks

using short8 = __attribute__((ext_vector_type(8))) short;
using f32x4 = __attribute__((ext_vector_type(4))) float;
typedef unsigned short u16;

__device__ __forceinline__ float b2f(unsigned short u) {
    unsigned v = (unsigned)u << 16;
    return __builtin_bit_cast(float, v);
}
__device__ __forceinline__ unsigned short f2b(float f) {
    return __builtin_bit_cast(unsigned short, __float2bfloat16(f));
}

struct EdgePtrs {
    const int* src[4];
    const int* dst[4];
    const float* val[4];
};

// ---------------- CSR build: bucketed counting sort (line-friendly writes) ------

__global__ void k_bhist(EdgePtrs ep, int* __restrict__ btot) {
    int r = blockIdx.y;
    const int* dst = ep.dst[r];
    __shared__ int h[NBUCK];
    int t = threadIdx.x;
    if (t < NBUCK) h[t] = 0;
    __syncthreads();
    int e0 = blockIdx.x * T1;
#pragma unroll
    for (int i = 0; i < T1 / 256; ++i) {
        int e = e0 + i * 256 + t;
        if (e < NE) atomicAdd(&h[dst[e] >> BSH], 1);
    }
    __syncthreads();
    if (t < NBUCK && h[t] > 0) atomicAdd(&btot[r * NBUCK + t], h[t]);
}

__global__ void k_bscan(const int* __restrict__ btot, int* __restrict__ bbase,
                        int* __restrict__ bcur) {
    __shared__ int s[128];
    int t = threadIdx.x;
    for (int r = 0; r < 4; ++r) {
        int v = (t < NBUCK) ? btot[r * NBUCK + t] : 0;
        if (t < 128) s[t] = v;
        __syncthreads();
        for (int off = 1; off < 128; off <<= 1) {
            int u = (t >= off && t < 128) ? s[t - off] : 0;
            __syncthreads();
            if (t < 128) s[t] += u;
            __syncthreads();
        }
        if (t < NBUCK) {
            int ex = s[t] - v;
            bbase[r * NBUCK + t] = ex;
            bcur[r * NBUCK + t] = ex;
        }
        __syncthreads();
    }
}

__global__ __launch_bounds__(256) void k_msplit(EdgePtrs ep, int* __restrict__ bcur,
                                                int2* __restrict__ esb) {
    int r = blockIdx.y;
    const int* src = ep.src[r];
    const int* dst = ep.dst[r];
    const float* val = ep.val[r];
    __shared__ int2 eb[T1];
    __shared__ int hist[128], lofs[128], lcur[128], sc[128], gbase[NBUCK];
    int t = threadIdx.x;
    int e0 = blockIdx.x * T1;
    int total = NE - e0;
    if (total > T1) total = T1;

    int sreg[T1 / 256], dreg[T1 / 256];
    float vreg[T1 / 256];
#pragma unroll
    for (int i = 0; i < T1 / 256; ++i) {
        int e = e0 + i * 256 + t;
        bool ok = e < NE;
        sreg[i] = ok ? src[e] : 0;
        dreg[i] = ok ? dst[e] : -1;
        vreg[i] = ok ? val[e] : 0.f;
    }
    if (t < 128) { hist[t] = 0; lcur[t] = 0; }
    __syncthreads();
#pragma unroll
    for (int i = 0; i < T1 / 256; ++i)
        if (dreg[i] >= 0) atomicAdd(&hist[dreg[i] >> BSH], 1);
    __syncthreads();
    if (t < 128) sc[t] = hist[t];
    __syncthreads();
    for (int off = 1; off < 128; off <<= 1) {
        int u = (t >= off && t < 128) ? sc[t - off] : 0;
        __syncthreads();
        if (t < 128) sc[t] += u;
        __syncthreads();
    }
    if (t < 128) lofs[t] = sc[t] - hist[t];
    __syncthreads();
#pragma unroll
    for (int i = 0; i < T1 / 256; ++i) {
        if (dreg[i] >= 0) {
            int b = dreg[i] >> BSH;
            int pos = lofs[b] + atomicAdd(&lcur[b], 1);
            eb[pos] = make_int2((int)(((unsigned)dreg[i] << 16) | (unsigned)sreg[i]),
                                __float_as_int(vreg[i]));
        }
    }
    __syncthreads();
    if (t < NBUCK && hist[t] > 0) gbase[t] = atomicAdd(&bcur[r * NBUCK + t], hist[t]);
    __syncthreads();
    for (int j = t; j < total; j += 256) {
        int2 rec = eb[j];
        int b = (int)((unsigned)rec.x >> (16 + BSH));
        esb[(size_t)r * NE + gbase[b] + (j - lofs[b])] = rec;
    }
}

__global__ __launch_bounds__(256) void k_blocal(const int2* __restrict__ esb,
                                                const int* __restrict__ btot,
                                                const int* __restrict__ bbase,
                                                int* __restrict__ rs4,
                                                int2* __restrict__ es4) {
    int r = blockIdx.y, b = blockIdx.x;
    int base = bbase[r * NBUCK + b];
    int cnt = btot[r * NBUCK + b];
    int d0 = b << BSH;
    int dlim = NN - d0;
    if (dlim > (1 << BSH)) dlim = 1 << BSH;
    __shared__ int h[512], pr[512], cur[512], ps[256];
    int t = threadIdx.x;
    h[t] = 0; h[t + 256] = 0;
    cur[t] = 0; cur[t + 256] = 0;
    __syncthreads();
    const int2* ein = esb + (size_t)r * NE + base;
    for (int j = t; j < cnt; j += 256)
        atomicAdd(&h[(int)((unsigned)ein[j].x >> 16) - d0], 1);
    __syncthreads();
    int a0 = h[2 * t], a1 = h[2 * t + 1];
    ps[t] = a0 + a1;
    __syncthreads();
    for (int off = 1; off < 256; off <<= 1) {
        int u = (t >= off) ? ps[t - off] : 0;
        __syncthreads();
        ps[t] += u;
        __syncthreads();
    }
    int ex = ps[t] - (a0 + a1);
    pr[2 * t] = ex;
    pr[2 * t + 1] = ex + a0;
    __syncthreads();
    for (int dl = t; dl < dlim; dl += 256) rs4[r * (NN + 1) + d0 + dl] = base + pr[dl];
    if (b == NBUCK - 1 && t == 0) rs4[r * (NN + 1) + NN] = NE;
    for (int j = t; j < cnt; j += 256) {
        int2 rec = ein[j];
        int dl = (int)((unsigned)rec.x >> 16) - d0;
        int k = atomicAdd(&cur[dl], 1);
        es4[(size_t)r * NE + base + pr[dl] + k] = make_int2(rec.x & 0xFFFF, rec.y);
    }
}

// ------------------------- fp32 -> bf16 bulk convert -------------------------

__global__ void k_f2b(const float* __restrict__ src, u16* __restrict__ dst, int n4) {
    int i = blockIdx.x * 256 + threadIdx.x;
    if (i >= n4) return;
    float4 v = ((const float4*)src)[i];
    unsigned lo = (unsigned)f2b(v.x) | ((unsigned)f2b(v.y) << 16);
    unsigned hi = (unsigned)f2b(v.z) | ((unsigned)f2b(v.w) << 16);
    ((uint2*)dst)[i] = make_uint2(lo, hi);
}

// ------------------------- weight transpose + swizzle pack -------------------------
// dst: bf16 at byte ((n*K + k)*2) ^ ((n&7)<<4)  -- matches GEMM's swizzled ds_read

struct WDesc { const float* src; u16* dst; int K; int N; int start; };
struct WPack { WDesc d[9]; };

__global__ void k_wt(WPack p) {
    int gid = blockIdx.x * 256 + threadIdx.x;
#pragma unroll
    for (int i = 0; i < 9; ++i) {
        int K = p.d[i].K, N = p.d[i].N;
        int local = gid - p.d[i].start;
        if (local >= 0 && local < K * N) {
            int k = local / N;
            int n = local - k * N;
            float w = p.d[i].src[local];
            unsigned byte = ((unsigned)(n * K + k) * 2u) ^ ((unsigned)(n & 7) << 4);
            *(u16*)((char*)p.d[i].dst + byte) = f2b(w);
            return;
        }
    }
}

// ------------------------- MFMA GEMM (optionally paired via gridDim.y) ----------
// MODE 0: Out = X@W + Bias ; MODE 1: relu ;
// MODE 2: Sout[blockIdx.x] = block partial of sum_rows(tanh(X@W+Bias)@Q)  (NO atomics)
template <int KT, int NF, int MODE, bool OUTF32>
__global__ __launch_bounds__(256) void k_mm(const u16* __restrict__ X0, const u16* __restrict__ X1,
                                            int M, const u16* __restrict__ WT,
                                            const float* __restrict__ Bias,
                                            const float* __restrict__ Q,
                                            void* __restrict__ O0, void* __restrict__ O1,
                                            float* __restrict__ S0, float* __restrict__ S1) {
    constexpr int K = KT * 32;
    constexpr int N = NF * 16;
    const u16* X = blockIdx.y ? X1 : X0;
    void* OutV = blockIdx.y ? O1 : O0;
    float* Sout = blockIdx.y ? S1 : S0;

    __shared__ u16 wlds[K * N];
    int t = threadIdx.x;
    constexpr int CH = K * N * 2 / 16;
    const uint4* wg = (const uint4*)WT;
    uint4* wl = (uint4*)wlds;
#pragma unroll
    for (int i = 0; i < CH / 256; ++i) wl[t + i * 256] = wg[t + i * 256];

    int l = t & 63, w = t >> 6;
    int m0 = blockIdx.x * 64 + w * 16;
    int arow = m0 + (l & 15);
    if (arow >= M) arow = M - 1;  // clamp; OOB rows masked in epilogue
    int kh = (l >> 4) * 8;

    short8 a[KT];
    const u16* xp = X + (size_t)arow * K + kh;
#pragma unroll
    for (int kt = 0; kt < KT; ++kt) a[kt] = *(const short8*)(xp + kt * 32);

    __syncthreads();

    f32x4 acc[NF];
#pragma unroll
    for (int i = 0; i < NF; ++i) acc[i] = (f32x4){0.f, 0.f, 0.f, 0.f};

    unsigned sw = (unsigned)((l & 7) << 4);
#pragma unroll
    for (int nf = 0; nf < NF; ++nf) {
        unsigned base = (unsigned)((nf * 16 + (l & 15)) * K) * 2u;
#pragma unroll
        for (int kt = 0; kt < KT; ++kt) {
            unsigned byte = (base + (unsigned)(kt * 32 + kh) * 2u) ^ sw;
            short8 b = *(const short8*)((const char*)wlds + byte);
            acc[nf] = __builtin_amdgcn_mfma_f32_16x16x32_bf16(a[kt], b, acc[nf], 0, 0, 0);
        }
    }

    // C/D layout: col=lane&15, row=(lane>>4)*4+r  [m89-verified]
    int col0 = l & 15;
    int rbase = m0 + (l >> 4) * 4;
    if (MODE == 2) {
        float tot = 0.f;
#pragma unroll
        for (int nf = 0; nf < NF; ++nf) {
            int c = nf * 16 + col0;
            float bv = Bias[c], qv = Q[c];
#pragma unroll
            for (int r = 0; r < 4; ++r)
                if (rbase + r < M) tot += tanhf(acc[nf][r] + bv) * qv;
        }
#pragma unroll
        for (int m = 1; m < 64; m <<= 1) tot += __shfl_xor(tot, m);
        __shared__ float wred[4];
        if (l == 0) wred[w] = tot;
        __syncthreads();
        if (t == 0) Sout[blockIdx.x] = wred[0] + wred[1] + wred[2] + wred[3];
    } else {
#pragma unroll
        for (int nf = 0; nf < NF; ++nf) {
            int c = nf * 16 + col0;
            float bv = Bias[c];
#pragma unroll
            for (int r = 0; r < 4; ++r) {
                int row = rbase + r;
                if (row >= M) continue;
                float v = acc[nf][r] + bv;
                if (MODE == 1) v = fmaxf(v, 0.f);
                if (OUTF32)
                    ((float*)OutV)[(size_t)row * N + c] = v;
                else
                    ((u16*)OutV)[(size_t)row * N + c] = f2b(v);
            }
        }
    }
}

// ------------------------- SpMM pair (bf16 gather, fp32 accum, unroll x4) -------
struct SpmmArgs {
    const int* rs0; const int2* es0; const u16* Xs0; const u16* Xd0;
    const float* a20; u16* out0;
    const int* rs1; const int2* es1; const u16* Xs1; const u16* Xd1;
    const float* a21; u16* out1;
};

__global__ void k_spmm2(SpmmArgs p) {
    int sel = blockIdx.y;
    const int* rs = sel ? p.rs1 : p.rs0;
    const int2* es = sel ? p.es1 : p.es0;
    const u16* Xs = sel ? p.Xs1 : p.Xs0;
    const u16* Xd = sel ? p.Xd1 : p.Xd0;
    const float* a2 = sel ? p.a21 : p.a20;
    u16* Out = sel ? p.out1 : p.out0;

    int row = blockIdx.x * 4 + (threadIdx.x >> 6);
    if (row >= NN) return;
    int lane = threadIdx.x & 63;
    int e0 = rs[row], e1 = rs[row + 1];
    float a = a2[row];
    unsigned xd = *(const unsigned*)&Xd[(size_t)row * DH + lane * 2];
    float accx = a * b2f((u16)xd);
    float accy = a * b2f((u16)(xd >> 16));

    int e = e0;
    for (; e + 4 <= e1; e += 4) {
        int2 p0 = es[e], p1 = es[e + 1], p2 = es[e + 2], p3 = es[e + 3];
        unsigned x0 = *(const unsigned*)&Xs[(size_t)p0.x * DH + lane * 2];
        unsigned x1 = *(const unsigned*)&Xs[(size_t)p1.x * DH + lane * 2];
        unsigned x2 = *(const unsigned*)&Xs[(size_t)p2.x * DH + lane * 2];
        unsigned x3 = *(const unsigned*)&Xs[(size_t)p3.x * DH + lane * 2];
        float v0 = __int_as_float(p0.y), v1 = __int_as_float(p1.y);
        float v2 = __int_as_float(p2.y), v3 = __int_as_float(p3.y);
        accx += v0 * b2f((u16)x0);
        accy += v0 * b2f((u16)(x0 >> 16));
        accx += v1 * b2f((u16)x1);
        accy += v1 * b2f((u16)(x1 >> 16));
        accx += v2 * b2f((u16)x2);
        accy += v2 * b2f((u16)(x2 >> 16));
        accx += v3 * b2f((u16)x3);
        accy += v3 * b2f((u16)(x3 >> 16));
    }
    for (; e < e1; ++e) {
        int2 pe = es[e];
        float v = __int_as_float(pe.y);
        unsigned xv = *(const unsigned*)&Xs[(size_t)pe.x * DH + lane * 2];
        accx += v * b2f((u16)xv);
        accy += v * b2f((u16)(xv >> 16));
    }
    unsigned o = (unsigned)f2b(accx) | ((unsigned)f2b(accy) << 16);
    *(unsigned*)&Out[(size_t)row * DH + lane * 2] = o;
}

// --------- combine: reduce score partials in-block, beta softmax, stream --------

__global__ void k_combine(const u16* __restrict__ h1, const u16* __restrict__ h2,
                          const float* __restrict__ sp, u16* __restrict__ out, int n8) {
    int t = threadIdx.x;
    float p0 = 0.f, p1 = 0.f;
    for (int j = t; j < GGC; j += 256) {
        p0 += sp[j];
        p1 += sp[GGC + j];
    }
#pragma unroll
    for (int m = 1; m < 64; m <<= 1) {
        p0 += __shfl_xor(p0, m);
        p1 += __shfl_xor(p1, m);
    }
    __shared__ float r0[4], r1[4];
    if ((t & 63) == 0) {
        r0[t >> 6] = p0;
        r1[t >> 6] = p1;
    }
    __syncthreads();
    float s0 = (r0[0] + r0[1] + r0[2] + r0[3]) * INV_N;
    float s1 = (r1[0] + r1[1] + r1[2] + r1[3]) * INV_N;
    float mx = fmaxf(s0, s1);
    float ea = __expf(s0 - mx), eb = __expf(s1 - mx);
    float inv = 1.0f / (ea + eb);
    float b0 = ea * inv, b1 = eb * inv;

    int i = blockIdx.x * 256 + t;
    if (i >= n8) return;
    short8 A = ((const short8*)h1)[i];
    short8 B = ((const short8*)h2)[i];
    short8 O;
#pragma unroll
    for (int j = 0; j < 8; ++j) {
        float v = b0 * b2f((u16)A[j]) + b1 * b2f((u16)B[j]);
        O[j] = (short)f2b(fmaxf(v, 0.f));
    }
    ((short8*)out)[i] = O;
}

// ------------------------- launch -------------------------

extern "C" void kernel_launch(void* const* d_in, const int* in_sizes, int n_in, void* d_out,
                              int out_size, void* d_ws, size_t ws_size, hipStream_t stream) {
    (void)in_sizes; (void)n_in; (void)out_size; (void)ws_size;

    const float* x_A = (const float*)d_in[0];
    const float* x_B = (const float*)d_in[1];
    EdgePtrs ep;
    const float* a2I[4];
    for (int r = 0; r < 4; ++r) {  // AA, AB, BB, BA
        ep.src[r] = (const int*)d_in[2 + r * 4];
        ep.dst[r] = (const int*)d_in[3 + r * 4];
        ep.val[r] = (const float*)d_in[4 + r * 4];
        a2I[r] = (const float*)d_in[5 + r * 4];
    }
    const float* fc1A_w = (const float*)d_in[18];
    const float* fc1A_b = (const float*)d_in[19];
    const float* fc1B_w = (const float*)d_in[20];
    const float* fc1B_b = (const float*)d_in[21];
    const float* fcs_w[2] = {(const float*)d_in[22], (const float*)d_in[30]};
    const float* fcs_b[2] = {(const float*)d_in[23], (const float*)d_in[31]};
    const float* saA_w[2] = {(const float*)d_in[24], (const float*)d_in[32]};
    const float* saA_b[2] = {(const float*)d_in[25], (const float*)d_in[33]};
    const float* saA_q[2] = {(const float*)d_in[26], (const float*)d_in[34]};
    const float* saB_w[2] = {(const float*)d_in[27], (const float*)d_in[35]};
    const float* saB_b[2] = {(const float*)d_in[28], (const float*)d_in[36]};
    const float* saB_q[2] = {(const float*)d_in[29], (const float*)d_in[37]};
    const float* fc2_w = (const float*)d_in[38];
    const float* fc2_b = (const float*)d_in[39];

    char* p = (char*)d_ws;
    auto take = [&](size_t bytes) -> void* {
        void* r = (void*)p;
        p += (bytes + 255) & ~(size_t)255;
        return r;
    };
    const size_t NF = (size_t)NN * DH;
    u16* xAbf = (u16*)take((size_t)NN * 256 * 2);
    u16* xBbf = (u16*)take((size_t)NN * 128 * 2);
    u16* xA0 = (u16*)take(NF * 2);
    u16* xA1 = (u16*)take(NF * 2);
    u16* xB0 = (u16*)take(NF * 2);
    u16* xB1 = (u16*)take(NF * 2);
    u16* h1 = (u16*)take(NF * 2);
    u16* h2 = (u16*)take(NF * 2);
    u16* wt_fc1A = (u16*)take(256 * 128 * 2);
    u16* wt_fc1B = (u16*)take(128 * 128 * 2);
    u16* wt_fcs[2] = {(u16*)take(128 * 128 * 2), (u16*)take(128 * 128 * 2)};
    u16* wt_saA[2] = {(u16*)take(128 * 128 * 2), (u16*)take(128 * 128 * 2)};
    u16* wt_saB[2] = {(u16*)take(128 * 128 * 2), (u16*)take(128 * 128 * 2)};
    u16* wt_fc2 = (u16*)take(128 * 64 * 2);
    int* rs4 = (int*)take((size_t)(NN + 1) * 4 * 4);
    int2* es4 = (int2*)take((size_t)NE * 4 * 8);
    int2* esb = (int2*)take((size_t)NE * 4 * 8);
    int* btot = (int*)take(NBUCK * 4 * 4);
    int* bbase = (int*)take(NBUCK * 4 * 4);
    int* bcur = (int*)take(NBUCK * 4 * 4);
    float* spart[4];  // per-(hop,type) score partials: [2][GGC]
    for (int i = 0; i < 4; ++i) spart[i] = (float*)take(2 * GGC * 4);

    const int GG = GGC;                   // 782
    const int GP = (NN + 3) / 4;          // 12500
    const int GC8 = (int)(NF / 8 / 256);  // 3125

    const int* rsR[4];
    const int2* esR[4];
    for (int r = 0; r < 4; ++r) {
        rsR[r] = rs4 + r * (NN + 1);
        esR[r] = es4 + (size_t)r * NE;
    }

    // ---- CSR build: bucketed counting sort ----
    hipMemsetAsync(btot, 0, NBUCK * 4 * 4, stream);
    k_bhist<<<dim3(NT1, 4), 256, 0, stream>>>(ep, btot);
    k_bscan<<<1, 256, 0, stream>>>(btot, bbase, bcur);
    k_msplit<<<dim3(NT1, 4), 256, 0, stream>>>(ep, bcur, esb);
    k_blocal<<<dim3(NBUCK, 4), 256, 0, stream>>>(esb, btot, bbase, rs4, es4);

    // ---- input conversion + weight packing ----
    k_f2b<<<(NN * 256 / 4 + 255) / 256, 256, 0, stream>>>(x_A, xAbf, NN * 256 / 4);
    k_f2b<<<(NN * 128 / 4 + 255) / 256, 256, 0, stream>>>(x_B, xBbf, NN * 128 / 4);
    {
        WPack wp;
        const float* srcs_[9] = {fc1A_w, fc1B_w, fcs_w[0], fcs_w[1], saA_w[0],
                                 saA_w[1], saB_w[0], saB_w[1], fc2_w};
        u16* dsts_[9] = {wt_fc1A, wt_fc1B, wt_fcs[0], wt_fcs[1], wt_saA[0],
                         wt_saA[1], wt_saB[0], wt_saB[1], wt_fc2};
        int Ks[9] = {256, 128, 128, 128, 128, 128, 128, 128, 128};
        int Ns[9] = {128, 128, 128, 128, 128, 128, 128, 128, 64};
        int start = 0;
        for (int i = 0; i < 9; ++i) {
            wp.d[i] = {srcs_[i], dsts_[i], Ks[i], Ns[i], start};
            start += Ks[i] * Ns[i];
        }
        k_wt<<<(start + 255) / 256, 256, 0, stream>>>(wp);
    }

    // ---- fc1 + relu ----
    k_mm<8, 8, 1, false><<<dim3(GG, 1), 256, 0, stream>>>(xAbf, xAbf, NN, wt_fc1A, fc1A_b,
                                                          nullptr, xA0, xA0, nullptr, nullptr);
    k_mm<4, 8, 1, false><<<dim3(GG, 1), 256, 0, stream>>>(xBbf, xBbf, NN, wt_fc1B, fc1B_b,
                                                          nullptr, xB0, xB0, nullptr, nullptr);

    for (int h = 0; h < 2; ++h) {
        // shared per-hop linear: xA1 = xA0@fcs+b, xB1 = xB0@fcs+b (one dispatch)
        k_mm<4, 8, 0, false><<<dim3(GG, 2), 256, 0, stream>>>(xA0, xB0, NN, wt_fcs[h], fcs_b[h],
                                                              nullptr, xA1, xB1, nullptr, nullptr);
        // type A: AA (r=0) -> h1, AB (r=1) -> h2
        {
            SpmmArgs sa = {rsR[0], esR[0], xA1, xA1, a2I[0], h1,
                           rsR[1], esR[1], xB1, xA1, a2I[1], h2};
            k_spmm2<<<dim3(GP, 2), 256, 0, stream>>>(sa);
        }
        k_mm<4, 8, 2, false><<<dim3(GG, 2), 256, 0, stream>>>(h1, h2, NN, wt_saA[h], saA_b[h],
                                                              saA_q[h], nullptr, nullptr,
                                                              spart[h * 2 + 0],
                                                              spart[h * 2 + 0] + GGC);
        k_combine<<<GC8, 256, 0, stream>>>(h1, h2, spart[h * 2 + 0], xA0, (int)(NF / 8));
        // type B: BB (r=2) -> h1, BA (r=3, gathers UPDATED xA0) -> h2
        {
            SpmmArgs sb = {rsR[2], esR[2], xB1, xB1, a2I[2], h1,
                           rsR[3], esR[3], xA0, xB1, a2I[3], h2};
            k_spmm2<<<dim3(GP, 2), 256, 0, stream>>>(sb);
        }
        k_mm<4, 8, 2, false><<<dim3(GG, 2), 256, 0, stream>>>(h1, h2, NN, wt_saB[h], saB_b[h],
                                                              saB_q[h], nullptr, nullptr,
                                                              spart[h * 2 + 1],
                                                              spart[h * 2 + 1] + GGC);
        k_combine<<<GC8, 256, 0, stream>>>(h1, h2, spart[h * 2 + 1], xB0, (int)(NF / 8));
    }

    // ---- fc2 (no relu), f32 out ----
    k_mm<4, 4, 0, true><<<dim3(GG, 1), 256, 0, stream>>>(xA0, xA0, NN, wt_fc2, fc2_b, nullptr,
                                                         d_out, d_out, nullptr, nullptr);
}

// Round 9
// 620.997 us; speedup vs baseline: 2.3837x; 1.0428x over previous
//
#include <hip/hip_runtime.h>
#include <hip/hip_bf16.h>

#define NN 50000
#define NE 500000
#define DH 128
#define INV_N (1.0f / 50000.0f)
#define NBUCK 98      // ceil(50000 / 512)
#define BSH 9         // bucket = dst >> 9
#define T1 4096       // edges per multisplit tile
#define NT1 ((NE + T1 - 1) / T1)  // 123
#define GGC 782       // (NN + 63) / 64 gemm blocks

using short8 = __attribute__((ext_vector_type(8))) short;
using f32x4 = __attribute__((ext_vector_type(4))) float;
typedef unsigned short u16;

__device__ __forceinline__ float b2f(unsigned short u) {
    unsigned v = (unsigned)u << 16;
    return __builtin_bit_cast(float, v);
}
__device__ __forceinline__ unsigned short f2b(float f) {
    return __builtin_bit_cast(unsigned short, __float2bfloat16(f));
}

struct EdgePtrs {
    const int* src[4];
    const int* dst[4];
    const float* val[4];
};

// ---------------- CSR build: bucketed counting sort (line-friendly writes) ------

__global__ void k_bhist(EdgePtrs ep, int* __restrict__ btot) {
    int r = blockIdx.y;
    const int* dst = ep.dst[r];
    __shared__ int h[NBUCK];
    int t = threadIdx.x;
    if (t < NBUCK) h[t] = 0;
    __syncthreads();
    int e0 = blockIdx.x * T1;
#pragma unroll
    for (int i = 0; i < T1 / 256; ++i) {
        int e = e0 + i * 256 + t;
        if (e < NE) atomicAdd(&h[dst[e] >> BSH], 1);
    }
    __syncthreads();
    if (t < NBUCK && h[t] > 0) atomicAdd(&btot[r * NBUCK + t], h[t]);
}

__global__ void k_bscan(const int* __restrict__ btot, int* __restrict__ bbase,
                        int* __restrict__ bcur) {
    __shared__ int s[128];
    int t = threadIdx.x;
    for (int r = 0; r < 4; ++r) {
        int v = (t < NBUCK) ? btot[r * NBUCK + t] : 0;
        if (t < 128) s[t] = v;
        __syncthreads();
        for (int off = 1; off < 128; off <<= 1) {
            int u = (t >= off && t < 128) ? s[t - off] : 0;
            __syncthreads();
            if (t < 128) s[t] += u;
            __syncthreads();
        }
        if (t < NBUCK) {
            int ex = s[t] - v;
            bbase[r * NBUCK + t] = ex;
            bcur[r * NBUCK + t] = ex;
        }
        __syncthreads();
    }
}

__global__ __launch_bounds__(256) void k_msplit(EdgePtrs ep, int* __restrict__ bcur,
                                                int2* __restrict__ esb) {
    int r = blockIdx.y;
    const int* src = ep.src[r];
    const int* dst = ep.dst[r];
    const float* val = ep.val[r];
    __shared__ int2 eb[T1];
    __shared__ int hist[128], lofs[128], lcur[128], sc[128], gbase[NBUCK];
    int t = threadIdx.x;
    int e0 = blockIdx.x * T1;
    int total = NE - e0;
    if (total > T1) total = T1;

    int sreg[T1 / 256], dreg[T1 / 256];
    float vreg[T1 / 256];
#pragma unroll
    for (int i = 0; i < T1 / 256; ++i) {
        int e = e0 + i * 256 + t;
        bool ok = e < NE;
        sreg[i] = ok ? src[e] : 0;
        dreg[i] = ok ? dst[e] : -1;
        vreg[i] = ok ? val[e] : 0.f;
    }
    if (t < 128) { hist[t] = 0; lcur[t] = 0; }
    __syncthreads();
#pragma unroll
    for (int i = 0; i < T1 / 256; ++i)
        if (dreg[i] >= 0) atomicAdd(&hist[dreg[i] >> BSH], 1);
    __syncthreads();
    if (t < 128) sc[t] = hist[t];
    __syncthreads();
    for (int off = 1; off < 128; off <<= 1) {
        int u = (t >= off && t < 128) ? sc[t - off] : 0;
        __syncthreads();
        if (t < 128) sc[t] += u;
        __syncthreads();
    }
    if (t < 128) lofs[t] = sc[t] - hist[t];
    __syncthreads();
#pragma unroll
    for (int i = 0; i < T1 / 256; ++i) {
        if (dreg[i] >= 0) {
            int b = dreg[i] >> BSH;
            int pos = lofs[b] + atomicAdd(&lcur[b], 1);
            eb[pos] = make_int2((int)(((unsigned)dreg[i] << 16) | (unsigned)sreg[i]),
                                __float_as_int(vreg[i]));
        }
    }
    __syncthreads();
    if (t < NBUCK && hist[t] > 0) gbase[t] = atomicAdd(&bcur[r * NBUCK + t], hist[t]);
    __syncthreads();
    for (int j = t; j < total; j += 256) {
        int2 rec = eb[j];
        int b = (int)((unsigned)rec.x >> (16 + BSH));
        esb[(size_t)r * NE + gbase[b] + (j - lofs[b])] = rec;
    }
}

__global__ __launch_bounds__(256) void k_blocal(const int2* __restrict__ esb,
                                                const int* __restrict__ btot,
                                                const int* __restrict__ bbase,
                                                int* __restrict__ rs4,
                                                int2* __restrict__ es4) {
    int r = blockIdx.y, b = blockIdx.x;
    int base = bbase[r * NBUCK + b];
    int cnt = btot[r * NBUCK + b];
    int d0 = b << BSH;
    int dlim = NN - d0;
    if (dlim > (1 << BSH)) dlim = 1 << BSH;
    __shared__ int h[512], pr[512], cur[512], ps[256];
    int t = threadIdx.x;
    h[t] = 0; h[t + 256] = 0;
    cur[t] = 0; cur[t + 256] = 0;
    __syncthreads();
    const int2* ein = esb + (size_t)r * NE + base;
    for (int j = t; j < cnt; j += 256)
        atomicAdd(&h[(int)((unsigned)ein[j].x >> 16) - d0], 1);
    __syncthreads();
    int a0 = h[2 * t], a1 = h[2 * t + 1];
    ps[t] = a0 + a1;
    __syncthreads();
    for (int off = 1; off < 256; off <<= 1) {
        int u = (t >= off) ? ps[t - off] : 0;
        __syncthreads();
        ps[t] += u;
        __syncthreads();
    }
    int ex = ps[t] - (a0 + a1);
    pr[2 * t] = ex;
    pr[2 * t + 1] = ex + a0;
    __syncthreads();
    for (int dl = t; dl < dlim; dl += 256) rs4[r * (NN + 1) + d0 + dl] = base + pr[dl];
    if (b == NBUCK - 1 && t == 0) rs4[r * (NN + 1) + NN] = NE;
    for (int j = t; j < cnt; j += 256) {
        int2 rec = ein[j];
        int dl = (int)((unsigned)rec.x >> 16) - d0;
        int k = atomicAdd(&cur[dl], 1);
        es4[(size_t)r * NE + base + pr[dl] + k] = make_int2(rec.x & 0xFFFF, rec.y);
    }
}

// ------------------------- fp32 -> bf16 bulk convert -------------------------

__global__ void k_f2b(const float* __restrict__ src, u16* __restrict__ dst, int n4) {
    int i = blockIdx.x * 256 + threadIdx.x;
    if (i >= n4) return;
    float4 v = ((const float4*)src)[i];
    unsigned lo = (unsigned)f2b(v.x) | ((unsigned)f2b(v.y) << 16);
    unsigned hi = (unsigned)f2b(v.z) | ((unsigned)f2b(v.w) << 16);
    ((uint2*)dst)[i] = make_uint2(lo, hi);
}

// ------------------------- weight transpose + swizzle pack -------------------------
// dst: bf16 at byte ((n*K + k)*2) ^ ((n&7)<<4)  -- matches GEMM's swizzled ds_read

struct WDesc { const float* src; u16* dst; int K; int N; int start; };
struct WPack { WDesc d[9]; };

__global__ void k_wt(WPack p) {
    int gid = blockIdx.x * 256 + threadIdx.x;
#pragma unroll
    for (int i = 0; i < 9; ++i) {
        int K = p.d[i].K, N = p.d[i].N;
        int local = gid - p.d[i].start;
        if (local >= 0 && local < K * N) {
            int k = local / N;
            int n = local - k * N;
            float w = p.d[i].src[local];
            unsigned byte = ((unsigned)(n * K + k) * 2u) ^ ((unsigned)(n & 7) << 4);
            *(u16*)((char*)p.d[i].dst + byte) = f2b(w);
            return;
        }
    }
}

// ------------------------- MFMA GEMM (optionally paired via gridDim.y) ----------
// MODE 0: Out = X@W + Bias ; MODE 1: relu ;
// MODE 2: Sout[blockIdx.x] = block partial of sum_rows(tanh(X@W+Bias)@Q)  (NO atomics)
template <int KT, int NF, int MODE, bool OUTF32>
__global__ __launch_bounds__(256) void k_mm(const u16* __restrict__ X0, const u16* __restrict__ X1,
                                            int M, const u16* __restrict__ WT,
                                            const float* __restrict__ Bias,
                                            const float* __restrict__ Q,
                                            void* __restrict__ O0, void* __restrict__ O1,
                                            float* __restrict__ S0, float* __restrict__ S1) {
    constexpr int K = KT * 32;
    constexpr int N = NF * 16;
    const u16* X = blockIdx.y ? X1 : X0;
    void* OutV = blockIdx.y ? O1 : O0;
    float* Sout = blockIdx.y ? S1 : S0;

    __shared__ u16 wlds[K * N];
    int t = threadIdx.x;
    constexpr int CH = K * N * 2 / 16;
    const uint4* wg = (const uint4*)WT;
    uint4* wl = (uint4*)wlds;
#pragma unroll
    for (int i = 0; i < CH / 256; ++i) wl[t + i * 256] = wg[t + i * 256];

    int l = t & 63, w = t >> 6;
    int m0 = blockIdx.x * 64 + w * 16;
    int arow = m0 + (l & 15);
    if (arow >= M) arow = M - 1;  // clamp; OOB rows masked in epilogue
    int kh = (l >> 4) * 8;

    short8 a[KT];
    const u16* xp = X + (size_t)arow * K + kh;
#pragma unroll
    for (int kt = 0; kt < KT; ++kt) a[kt] = *(const short8*)(xp + kt * 32);

    __syncthreads();

    f32x4 acc[NF];
#pragma unroll
    for (int i = 0; i < NF; ++i) acc[i] = (f32x4){0.f, 0.f, 0.f, 0.f};

    unsigned sw = (unsigned)((l & 7) << 4);
#pragma unroll
    for (int nf = 0; nf < NF; ++nf) {
        unsigned base = (unsigned)((nf * 16 + (l & 15)) * K) * 2u;
#pragma unroll
        for (int kt = 0; kt < KT; ++kt) {
            unsigned byte = (base + (unsigned)(kt * 32 + kh) * 2u) ^ sw;
            short8 b = *(const short8*)((const char*)wlds + byte);
            acc[nf] = __builtin_amdgcn_mfma_f32_16x16x32_bf16(a[kt], b, acc[nf], 0, 0, 0);
        }
    }

    // C/D layout: col=lane&15, row=(lane>>4)*4+r  [m89-verified]
    int col0 = l & 15;
    int rbase = m0 + (l >> 4) * 4;
    if (MODE == 2) {
        float tot = 0.f;
#pragma unroll
        for (int nf = 0; nf < NF; ++nf) {
            int c = nf * 16 + col0;
            float bv = Bias[c], qv = Q[c];
#pragma unroll
            for (int r = 0; r < 4; ++r)
                if (rbase + r < M) tot += tanhf(acc[nf][r] + bv) * qv;
        }
#pragma unroll
        for (int m = 1; m < 64; m <<= 1) tot += __shfl_xor(tot, m);
        __shared__ float wred[4];
        if (l == 0) wred[w] = tot;
        __syncthreads();
        if (t == 0) Sout[blockIdx.x] = wred[0] + wred[1] + wred[2] + wred[3];
    } else {
#pragma unroll
        for (int nf = 0; nf < NF; ++nf) {
            int c = nf * 16 + col0;
            float bv = Bias[c];
#pragma unroll
            for (int r = 0; r < 4; ++r) {
                int row = rbase + r;
                if (row >= M) continue;
                float v = acc[nf][r] + bv;
                if (MODE == 1) v = fmaxf(v, 0.f);
                if (OUTF32)
                    ((float*)OutV)[(size_t)row * N + c] = v;
                else
                    ((u16*)OutV)[(size_t)row * N + c] = f2b(v);
            }
        }
    }
}

// ---------- SpMM dual-relation (one wave per dst row, both relations) ----------
// out1[i] = a2A[i]*Xd[i] + sum_{e in rowA i} valA[e]*XsA[srcA[e]]
// out2[i] = a2B[i]*Xd[i] + sum_{e in rowB i} valB[e]*XsB[srcB[e]]
struct SpmmDArgs {
    const int* rsA; const int2* esA; const u16* XsA;
    const int* rsB; const int2* esB; const u16* XsB;
    const u16* Xd; const float* a2A; const float* a2B;
    u16* out1; u16* out2;
};

__device__ __forceinline__ void gacc(const u16* __restrict__ Xs, int lane, int2 pe,
                                     float& ax, float& ay) {
    unsigned xv = *(const unsigned*)&Xs[(size_t)pe.x * DH + lane * 2];
    float v = __int_as_float(pe.y);
    ax += v * b2f((u16)xv);
    ay += v * b2f((u16)(xv >> 16));
}

__global__ __launch_bounds__(256) void k_spmmD(SpmmDArgs p) {
    int row = blockIdx.x * 4 + (threadIdx.x >> 6);
    if (row >= NN) return;
    int lane = threadIdx.x & 63;
    unsigned xd = *(const unsigned*)&p.Xd[(size_t)row * DH + lane * 2];
    float xdx = b2f((u16)xd), xdy = b2f((u16)(xd >> 16));
    float aA = p.a2A[row], aB = p.a2B[row];
    float a1x = aA * xdx, a1y = aA * xdy;
    float a2x = aB * xdx, a2y = aB * xdy;
    int eA = p.rsA[row], eAe = p.rsA[row + 1];
    int eB = p.rsB[row], eBe = p.rsB[row + 1];

    // fused main loop: 8 gathers in flight (4 per relation)
    while (eA + 4 <= eAe && eB + 4 <= eBe) {
        int2 pa0 = p.esA[eA], pa1 = p.esA[eA + 1], pa2 = p.esA[eA + 2], pa3 = p.esA[eA + 3];
        int2 pb0 = p.esB[eB], pb1 = p.esB[eB + 1], pb2 = p.esB[eB + 2], pb3 = p.esB[eB + 3];
        unsigned xa0 = *(const unsigned*)&p.XsA[(size_t)pa0.x * DH + lane * 2];
        unsigned xa1 = *(const unsigned*)&p.XsA[(size_t)pa1.x * DH + lane * 2];
        unsigned xa2 = *(const unsigned*)&p.XsA[(size_t)pa2.x * DH + lane * 2];
        unsigned xa3 = *(const unsigned*)&p.XsA[(size_t)pa3.x * DH + lane * 2];
        unsigned xb0 = *(const unsigned*)&p.XsB[(size_t)pb0.x * DH + lane * 2];
        unsigned xb1 = *(const unsigned*)&p.XsB[(size_t)pb1.x * DH + lane * 2];
        unsigned xb2 = *(const unsigned*)&p.XsB[(size_t)pb2.x * DH + lane * 2];
        unsigned xb3 = *(const unsigned*)&p.XsB[(size_t)pb3.x * DH + lane * 2];
        float va0 = __int_as_float(pa0.y), va1 = __int_as_float(pa1.y);
        float va2 = __int_as_float(pa2.y), va3 = __int_as_float(pa3.y);
        float vb0 = __int_as_float(pb0.y), vb1 = __int_as_float(pb1.y);
        float vb2 = __int_as_float(pb2.y), vb3 = __int_as_float(pb3.y);
        a1x += va0 * b2f((u16)xa0); a1y += va0 * b2f((u16)(xa0 >> 16));
        a1x += va1 * b2f((u16)xa1); a1y += va1 * b2f((u16)(xa1 >> 16));
        a1x += va2 * b2f((u16)xa2); a1y += va2 * b2f((u16)(xa2 >> 16));
        a1x += va3 * b2f((u16)xa3); a1y += va3 * b2f((u16)(xa3 >> 16));
        a2x += vb0 * b2f((u16)xb0); a2y += vb0 * b2f((u16)(xb0 >> 16));
        a2x += vb1 * b2f((u16)xb1); a2y += vb1 * b2f((u16)(xb1 >> 16));
        a2x += vb2 * b2f((u16)xb2); a2y += vb2 * b2f((u16)(xb2 >> 16));
        a2x += vb3 * b2f((u16)xb3); a2y += vb3 * b2f((u16)(xb3 >> 16));
        eA += 4; eB += 4;
    }
    // drain A
    for (; eA + 4 <= eAe; eA += 4) {
        int2 q0 = p.esA[eA], q1 = p.esA[eA + 1], q2 = p.esA[eA + 2], q3 = p.esA[eA + 3];
        gacc(p.XsA, lane, q0, a1x, a1y);
        gacc(p.XsA, lane, q1, a1x, a1y);
        gacc(p.XsA, lane, q2, a1x, a1y);
        gacc(p.XsA, lane, q3, a1x, a1y);
    }
    for (; eA < eAe; ++eA) gacc(p.XsA, lane, p.esA[eA], a1x, a1y);
    // drain B
    for (; eB + 4 <= eBe; eB += 4) {
        int2 q0 = p.esB[eB], q1 = p.esB[eB + 1], q2 = p.esB[eB + 2], q3 = p.esB[eB + 3];
        gacc(p.XsB, lane, q0, a2x, a2y);
        gacc(p.XsB, lane, q1, a2x, a2y);
        gacc(p.XsB, lane, q2, a2x, a2y);
        gacc(p.XsB, lane, q3, a2x, a2y);
    }
    for (; eB < eBe; ++eB) gacc(p.XsB, lane, p.esB[eB], a2x, a2y);

    unsigned o1 = (unsigned)f2b(a1x) | ((unsigned)f2b(a1y) << 16);
    unsigned o2 = (unsigned)f2b(a2x) | ((unsigned)f2b(a2y) << 16);
    *(unsigned*)&p.out1[(size_t)row * DH + lane * 2] = o1;
    *(unsigned*)&p.out2[(size_t)row * DH + lane * 2] = o2;
}

// --------- combine: reduce score partials in-block, beta softmax, stream --------

__global__ void k_combine(const u16* __restrict__ h1, const u16* __restrict__ h2,
                          const float* __restrict__ sp, u16* __restrict__ out, int n8) {
    int t = threadIdx.x;
    float p0 = 0.f, p1 = 0.f;
    for (int j = t; j < GGC; j += 256) {
        p0 += sp[j];
        p1 += sp[GGC + j];
    }
#pragma unroll
    for (int m = 1; m < 64; m <<= 1) {
        p0 += __shfl_xor(p0, m);
        p1 += __shfl_xor(p1, m);
    }
    __shared__ float r0[4], r1[4];
    if ((t & 63) == 0) {
        r0[t >> 6] = p0;
        r1[t >> 6] = p1;
    }
    __syncthreads();
    float s0 = (r0[0] + r0[1] + r0[2] + r0[3]) * INV_N;
    float s1 = (r1[0] + r1[1] + r1[2] + r1[3]) * INV_N;
    float mx = fmaxf(s0, s1);
    float ea = __expf(s0 - mx), eb = __expf(s1 - mx);
    float inv = 1.0f / (ea + eb);
    float b0 = ea * inv, b1 = eb * inv;

    int i = blockIdx.x * 256 + t;
    if (i >= n8) return;
    short8 A = ((const short8*)h1)[i];
    short8 B = ((const short8*)h2)[i];
    short8 O;
#pragma unroll
    for (int j = 0; j < 8; ++j) {
        float v = b0 * b2f((u16)A[j]) + b1 * b2f((u16)B[j]);
        O[j] = (short)f2b(fmaxf(v, 0.f));
    }
    ((short8*)out)[i] = O;
}

// ------------------------- launch -------------------------

extern "C" void kernel_launch(void* const* d_in, const int* in_sizes, int n_in, void* d_out,
                              int out_size, void* d_ws, size_t ws_size, hipStream_t stream) {
    (void)in_sizes; (void)n_in; (void)out_size; (void)ws_size;

    const float* x_A = (const float*)d_in[0];
    const float* x_B = (const float*)d_in[1];
    EdgePtrs ep;
    const float* a2I[4];
    for (int r = 0; r < 4; ++r) {  // AA, AB, BB, BA
        ep.src[r] = (const int*)d_in[2 + r * 4];
        ep.dst[r] = (const int*)d_in[3 + r * 4];
        ep.val[r] = (const float*)d_in[4 + r * 4];
        a2I[r] = (const float*)d_in[5 + r * 4];
    }
    const float* fc1A_w = (const float*)d_in[18];
    const float* fc1A_b = (const float*)d_in[19];
    const float* fc1B_w = (const float*)d_in[20];
    const float* fc1B_b = (const float*)d_in[21];
    const float* fcs_w[2] = {(const float*)d_in[22], (const float*)d_in[30]};
    const float* fcs_b[2] = {(const float*)d_in[23], (const float*)d_in[31]};
    const float* saA_w[2] = {(const float*)d_in[24], (const float*)d_in[32]};
    const float* saA_b[2] = {(const float*)d_in[25], (const float*)d_in[33]};
    const float* saA_q[2] = {(const float*)d_in[26], (const float*)d_in[34]};
    const float* saB_w[2] = {(const float*)d_in[27], (const float*)d_in[35]};
    const float* saB_b[2] = {(const float*)d_in[28], (const float*)d_in[36]};
    const float* saB_q[2] = {(const float*)d_in[29], (const float*)d_in[37]};
    const float* fc2_w = (const float*)d_in[38];
    const float* fc2_b = (const float*)d_in[39];

    char* p = (char*)d_ws;
    auto take = [&](size_t bytes) -> void* {
        void* r = (void*)p;
        p += (bytes + 255) & ~(size_t)255;
        return r;
    };
    const size_t NF = (size_t)NN * DH;
    u16* xAbf = (u16*)take((size_t)NN * 256 * 2);
    u16* xBbf = (u16*)take((size_t)NN * 128 * 2);
    u16* xA0 = (u16*)take(NF * 2);
    u16* xA1 = (u16*)take(NF * 2);
    u16* xB0 = (u16*)take(NF * 2);
    u16* xB1 = (u16*)take(NF * 2);
    u16* h1 = (u16*)take(NF * 2);
    u16* h2 = (u16*)take(NF * 2);
    u16* wt_fc1A = (u16*)take(256 * 128 * 2);
    u16* wt_fc1B = (u16*)take(128 * 128 * 2);
    u16* wt_fcs[2] = {(u16*)take(128 * 128 * 2), (u16*)take(128 * 128 * 2)};
    u16* wt_saA[2] = {(u16*)take(128 * 128 * 2), (u16*)take(128 * 128 * 2)};
    u16* wt_saB[2] = {(u16*)take(128 * 128 * 2), (u16*)take(128 * 128 * 2)};
    u16* wt_fc2 = (u16*)take(128 * 64 * 2);
    int* rs4 = (int*)take((size_t)(NN + 1) * 4 * 4);
    int2* es4 = (int2*)take((size_t)NE * 4 * 8);
    int2* esb = (int2*)take((size_t)NE * 4 * 8);
    int* btot = (int*)take(NBUCK * 4 * 4);
    int* bbase = (int*)take(NBUCK * 4 * 4);
    int* bcur = (int*)take(NBUCK * 4 * 4);
    float* spart[4];  // per-(hop,type) score partials: [2][GGC]
    for (int i = 0; i < 4; ++i) spart[i] = (float*)take(2 * GGC * 4);

    const int GG = GGC;                   // 782
    const int GP = (NN + 3) / 4;          // 12500
    const int GC8 = (int)(NF / 8 / 256);  // 3125

    const int* rsR[4];
    const int2* esR[4];
    for (int r = 0; r < 4; ++r) {
        rsR[r] = rs4 + r * (NN + 1);
        esR[r] = es4 + (size_t)r * NE;
    }

    // ---- CSR build: bucketed counting sort ----
    hipMemsetAsync(btot, 0, NBUCK * 4 * 4, stream);
    k_bhist<<<dim3(NT1, 4), 256, 0, stream>>>(ep, btot);
    k_bscan<<<1, 256, 0, stream>>>(btot, bbase, bcur);
    k_msplit<<<dim3(NT1, 4), 256, 0, stream>>>(ep, bcur, esb);
    k_blocal<<<dim3(NBUCK, 4), 256, 0, stream>>>(esb, btot, bbase, rs4, es4);

    // ---- input conversion + weight packing ----
    k_f2b<<<(NN * 256 / 4 + 255) / 256, 256, 0, stream>>>(x_A, xAbf, NN * 256 / 4);
    k_f2b<<<(NN * 128 / 4 + 255) / 256, 256, 0, stream>>>(x_B, xBbf, NN * 128 / 4);
    {
        WPack wp;
        const float* srcs_[9] = {fc1A_w, fc1B_w, fcs_w[0], fcs_w[1], saA_w[0],
                                 saA_w[1], saB_w[0], saB_w[1], fc2_w};
        u16* dsts_[9] = {wt_fc1A, wt_fc1B, wt_fcs[0], wt_fcs[1], wt_saA[0],
                         wt_saA[1], wt_saB[0], wt_saB[1], wt_fc2};
        int Ks[9] = {256, 128, 128, 128, 128, 128, 128, 128, 128};
        int Ns[9] = {128, 128, 128, 128, 128, 128, 128, 128, 64};
        int start = 0;
        for (int i = 0; i < 9; ++i) {
            wp.d[i] = {srcs_[i], dsts_[i], Ks[i], Ns[i], start};
            start += Ks[i] * Ns[i];
        }
        k_wt<<<(start + 255) / 256, 256, 0, stream>>>(wp);
    }

    // ---- fc1 + relu ----
    k_mm<8, 8, 1, false><<<dim3(GG, 1), 256, 0, stream>>>(xAbf, xAbf, NN, wt_fc1A, fc1A_b,
                                                          nullptr, xA0, xA0, nullptr, nullptr);
    k_mm<4, 8, 1, false><<<dim3(GG, 1), 256, 0, stream>>>(xBbf, xBbf, NN, wt_fc1B, fc1B_b,
                                                          nullptr, xB0, xB0, nullptr, nullptr);

    for (int h = 0; h < 2; ++h) {
        // shared per-hop linear: xA1 = xA0@fcs+b, xB1 = xB0@fcs+b (one dispatch)
        k_mm<4, 8, 0, false><<<dim3(GG, 2), 256, 0, stream>>>(xA0, xB0, NN, wt_fcs[h], fcs_b[h],
                                                              nullptr, xA1, xB1, nullptr, nullptr);
        // type A: AA (r=0) -> h1, AB (r=1) -> h2, both per wave
        {
            SpmmDArgs sa = {rsR[0], esR[0], xA1, rsR[1], esR[1], xB1,
                            xA1, a2I[0], a2I[1], h1, h2};
            k_spmmD<<<GP, 256, 0, stream>>>(sa);
        }
        k_mm<4, 8, 2, false><<<dim3(GG, 2), 256, 0, stream>>>(h1, h2, NN, wt_saA[h], saA_b[h],
                                                              saA_q[h], nullptr, nullptr,
                                                              spart[h * 2 + 0],
                                                              spart[h * 2 + 0] + GGC);
        k_combine<<<GC8, 256, 0, stream>>>(h1, h2, spart[h * 2 + 0], xA0, (int)(NF / 8));
        // type B: BB (r=2) -> h1, BA (r=3, gathers UPDATED xA0) -> h2
        {
            SpmmDArgs sb = {rsR[2], esR[2], xB1, rsR[3], esR[3], xA0,
                            xB1, a2I[2], a2I[3], h1, h2};
            k_spmmD<<<GP, 256, 0, stream>>>(sb);
        }
        k_mm<4, 8, 2, false><<<dim3(GG, 2), 256, 0, stream>>>(h1, h2, NN, wt_saB[h], saB_b[h],
                                                              saB_q[h], nullptr, nullptr,
                                                              spart[h * 2 + 1],
                                                              spart[h * 2 + 1] + GGC);
        k_combine<<<GC8, 256, 0, stream>>>(h1, h2, spart[h * 2 + 1], xB0, (int)(NF / 8));
    }

    // ---- fc2 (no relu), f32 out ----
    k_mm<4, 4, 0, true><<<dim3(GG, 1), 256, 0, stream>>>(xA0, xA0, NN, wt_fc2, fc2_b, nullptr,
                                                         d_out, d_out, nullptr, nullptr);
}